// Round 6
// baseline (374.214 us; speedup 1.0000x reference)
//
#include <hip/hip_runtime.h>

typedef unsigned short u16;
typedef unsigned int u32;
typedef __bf16 bf16x8 __attribute__((ext_vector_type(8)));
typedef float f32x4 __attribute__((ext_vector_type(4)));
typedef u16 u16x4 __attribute__((ext_vector_type(4)));
typedef __attribute__((address_space(1))) void* as1_t;
typedef __attribute__((address_space(3))) void* as3_t;

#define LOG2E 1.4426950408889634f
#define MFMA(a,b,c) __builtin_amdgcn_mfma_f32_16x16x32_bf16(a,b,c,0,0,0)

__device__ __forceinline__ u16 f2bf(float f){
  u32 u = __float_as_uint(f);
  return (u16)((u + 0x7FFFu + ((u >> 16) & 1u)) >> 16);
}
__device__ __forceinline__ float bf2f(u16 x){
  return __uint_as_float(((u32)x) << 16);
}
#if __has_builtin(__builtin_amdgcn_cvt_pk_bf16_f32)
__device__ __forceinline__ u16x4 pk4(float a, float b, float c, float d){
  auto lo = __builtin_amdgcn_cvt_pk_bf16_f32(a,b);
  auto hi = __builtin_amdgcn_cvt_pk_bf16_f32(c,d);
  union { u16x4 v; u32 w[2]; } u;
  u.w[0] = __builtin_bit_cast(u32, lo);
  u.w[1] = __builtin_bit_cast(u32, hi);
  return u.v;
}
#else
__device__ __forceinline__ u16x4 pk4(float a, float b, float c, float d){
  u16x4 r = { f2bf(a), f2bf(b), f2bf(c), f2bf(d) };
  return r;
}
#endif
__device__ __forceinline__ void gld16(const u16* gp, u16* lp){
  __builtin_amdgcn_global_load_lds((as1_t)(u16*)gp, (as3_t)lp, 16, 0, 0);
}

#define SBAR  __builtin_amdgcn_s_barrier()
#define SCHB  __builtin_amdgcn_sched_barrier(0)
#define SP1   __builtin_amdgcn_s_setprio(1)
#define SP0   __builtin_amdgcn_s_setprio(0)
#define WAITL0 asm volatile("s_waitcnt lgkmcnt(0)" ::: "memory")
#define WAITV6 asm volatile("s_waitcnt vmcnt(6)" ::: "memory")
#define WV0 asm volatile("s_waitcnt vmcnt(0)" ::: "memory")
#define WV8 asm volatile("s_waitcnt vmcnt(8)" ::: "memory")

// ---------------- prep: cast both inputs + all 5 weight transposes, ONE launch ----------------
__global__ void prep_kernel(const float* __restrict__ vis, u16* __restrict__ vis16,
                            const float* __restrict__ txt, u16* __restrict__ txt16,
                            const float* __restrict__ Wq, const float* __restrict__ Wk,
                            const float* __restrict__ Wv, const float* __restrict__ Wo,
                            u16* __restrict__ T0, u16* __restrict__ T1,
                            u16* __restrict__ T2, u16* __restrict__ T3,
                            u16* __restrict__ T4){
  int bid = blockIdx.x;
  if(bid < 8192){
    const float* src = (bid < 4096) ? vis : txt;
    u16* dst = (bid < 4096) ? vis16 : txt16;
    int idx = ((bid & 4095)*256 + threadIdx.x)*4;
    float4 v = *(const float4*)(src + idx);
    *(u16x4*)(dst + idx) = pk4(v.x, v.y, v.z, v.w);
    return;
  }
  int rr = bid - 8192;
  int wi = rr >> 8, tile = rr & 255;
  const float* W; u16* WT;
  switch(wi){
    case 0: W = Wq; WT = T0; break;
    case 1: W = Wv; WT = T1; break;
    case 2: W = Wk; WT = T2; break;
    case 3: W = Wv; WT = T3; break;
    default: W = Wo; WT = T4; break;
  }
  __shared__ u16 t[64][65];
  int bn = (tile & 15)*64, bk = (tile >> 4)*64;
  int c = threadIdx.x & 63, r0 = threadIdx.x >> 6;
  #pragma unroll
  for(int j=0;j<64;j+=4){
    int r = r0 + j;
    t[r][c] = f2bf(W[(bk + r)*1024 + bn + c]);
  }
  __syncthreads();
  #pragma unroll
  for(int j=0;j<64;j+=4){
    int r = r0 + j;
    WT[(bn + r)*1024 + bk + c] = t[c][r];
  }
}

// ======== shared macros for proj kernel + probes (round-3 structure, 256x256, BK=64) =========
#define STG(G, gbase, dsto, kk) { \
    _Pragma("unroll") \
    for(int ii=0;ii<4;ii++){ \
      int slot_ = ii*512 + tid; int r_ = slot_ >> 3, cs_ = slot_ & 7; \
      gld16((G) + (size_t)((gbase) + r_)*1024 + (kk) + ((cs_ ^ (r_ & 7)) << 3), \
            lds + (dsto) + (ii*512 + (w << 6))*8); } }

#define LDA_(bo, mh) { \
    _Pragma("unroll") \
    for(int q_=0;q_<4;q_++){ \
      int ro_ = (bo) + arow + (((mh)*4 + q_) << 10); \
      af[q_][0] = *(const bf16x8*)(lds + ro_ + sx0); \
      af[q_][1] = *(const bf16x8*)(lds + ro_ + sx1); } }

#define LDB_(bo, nh, bfv) { \
    _Pragma("unroll") \
    for(int j_=0;j_<2;j_++){ \
      int ro_ = (bo) + brow + (((nh)*2 + j_) << 10); \
      bfv[j_][0] = *(const bf16x8*)(lds + ro_ + sx0); \
      bfv[j_][1] = *(const bf16x8*)(lds + ro_ + sx1); } }

#define MM_(mh, bfv, nh) { \
    _Pragma("unroll") \
    for(int q_=0;q_<4;q_++) \
      _Pragma("unroll") \
      for(int j_=0;j_<2;j_++){ \
        acc[(mh)*4+q_][(nh)*2+j_] = MFMA(af[q_][0], bfv[j_][0], acc[(mh)*4+q_][(nh)*2+j_]); \
        acc[(mh)*4+q_][(nh)*2+j_] = MFMA(af[q_][1], bfv[j_][1], acc[(mh)*4+q_][(nh)*2+j_]); } }

// ---------------- merged projection GEMM (round-3, known 43.4 us): 2-buf 4-phase -------------
// grid (16 m, 8 n, 2 z): bid%8 = m%8 -> A-panel sharers co-located per XCD.
__global__ __launch_bounds__(512, 2)
void proj_gemm_kernel(const u16* __restrict__ Avis, const u16* __restrict__ Atxt,
                      const u16* __restrict__ Wvis, const u16* __restrict__ Wtxt,
                      u16* __restrict__ Qb, u16* __restrict__ V2t,
                      u16* __restrict__ Kb, u16* __restrict__ Vt)
{
  const u16 *A, *Bt; u16 *Cn, *Ct;
  if(blockIdx.z == 0){ A = Avis; Bt = Wvis; Cn = Qb; Ct = V2t; }
  else               { A = Atxt; Bt = Wtxt; Cn = Kb; Ct = Vt;  }
  __shared__ u16 lds[65536];
  const int tid = threadIdx.x, w = tid >> 6, lane = tid & 63;
  const int quad = lane >> 4, cl = lane & 15;
  const int wr = w >> 2, wc = w & 3;
  const int bm = blockIdx.x*256, bn = blockIdx.y*256;
  const int sx0 = ((quad    ) ^ (cl & 7)) << 3;
  const int sx1 = ((quad + 4) ^ (cl & 7)) << 3;
  const int arow = ((wr << 7) + cl) << 6;
  const int brow = (((wc << 6) + cl) << 6) + 16384;

  f32x4 acc[8][4];
  #pragma unroll
  for(int a=0;a<8;a++)
    #pragma unroll
    for(int b=0;b<4;b++){ f32x4 z = {0.f,0.f,0.f,0.f}; acc[a][b] = z; }
  bf16x8 af[4][2], bfv0[2][2], bfv1[2][2];

#define TILE(bufo, ts) { \
    LDA_(bufo, 0); LDB_(bufo, 0, bfv0); \
    SBAR; WAITL0; SCHB; SP1; MM_(0, bfv0, 0); SP0; SBAR; \
    LDB_(bufo, 1, bfv1); \
    SBAR; WAITL0; SCHB; SP1; MM_(0, bfv1, 1); SP0; SBAR; \
    LDA_(bufo, 1); \
    SBAR; WAITL0; SCHB; SP1; MM_(1, bfv1, 1); SP0; SBAR; \
    STG(A , bm, (bufo)        , ts); \
    STG(Bt, bn, (bufo) + 16384, ts); \
    SCHB; SP1; MM_(1, bfv0, 0); SP0; \
    WV8; SBAR; }

  STG(A , bm, 0,     0);  STG(Bt, bn, 16384, 0);
  STG(A , bm, 32768, 64); STG(Bt, bn, 32768+16384, 64);
  WV8; SBAR;

  for(int tt=0; tt<8; tt++){
    const int t0 = 2*tt;
    TILE(0,     ((t0+2)&15) << 6);
    TILE(32768, ((t0+3)&15) << 6);
  }
#undef TILE

  if(bn < 1024){
    #pragma unroll
    for(int mf=0; mf<8; mf++){
      int m0 = bm + wr*128 + mf*16 + quad*4;
      #pragma unroll
      for(int nf=0; nf<4; nf++){
        int n = bn + wc*64 + nf*16 + cl;
        int h = n >> 6, d = n & 63;
        #pragma unroll
        for(int i2=0;i2<4;i2++){
          int m = m0 + i2; int b = m >> 10, s = m & 1023;
          Cn[(((size_t)(b*16 + h)*1024 + s) << 6) + d] = f2bf(acc[mf][nf][i2]);
        }
      }
    }
  } else {
    #pragma unroll
    for(int mf=0; mf<8; mf++){
      int m0 = bm + wr*128 + mf*16 + quad*4;
      int b = m0 >> 10, s = m0 & 1023;
      #pragma unroll
      for(int nf=0; nf<4; nf++){
        int nn = bn - 1024 + wc*64 + nf*16 + cl;
        int h = nn >> 6, d = nn & 63;
        *(u16x4*)(Ct + (((size_t)(b*16 + h)*64 + d) << 10) + s) =
            pk4(acc[mf][nf][0], acc[mf][nf][1], acc[mf][nf][2], acc[mf][nf][3]);
      }
    }
  }
}

// ---------------- DIAGNOSTIC PROBES (timing-only; no output writes; removed next round) ------
// V=2: ds_read+MFMA only (no staging) | V=3: staging only | V=4: MFMA only. REPS=3 each.
template<int V>
__global__ __launch_bounds__(512, 2)
void proj_probe(const u16* __restrict__ Avis, const u16* __restrict__ Atxt,
                const u16* __restrict__ Wvis, const u16* __restrict__ Wtxt)
{
  const u16 *A, *Bt;
  if(blockIdx.z == 0){ A = Avis; Bt = Wvis; }
  else               { A = Atxt; Bt = Wtxt; }
  __shared__ u16 lds[65536];
  const int tid = threadIdx.x, w = tid >> 6, lane = tid & 63;
  const int quad = lane >> 4, cl = lane & 15;
  const int bm = blockIdx.x*256, bn = blockIdx.y*256;
  const int sx0 = ((quad    ) ^ (cl & 7)) << 3;
  const int sx1 = ((quad + 4) ^ (cl & 7)) << 3;
  const int wr = (tid >> 6) >> 2, wc = (tid >> 6) & 3;
  const int arow = ((wr << 7) + cl) << 6;
  const int brow = (((wc << 6) + cl) << 6) + 16384;

  f32x4 acc[8][4];
  #pragma unroll
  for(int a=0;a<8;a++)
    #pragma unroll
    for(int b=0;b<4;b++){ f32x4 z = {0.f,0.f,0.f,0.f}; acc[a][b] = z; }
  bf16x8 af[4][2], bfv0[2][2], bfv1[2][2];

  STG(A , bm, 0,     0);  STG(Bt, bn, 16384, 0);
  WV0; SBAR;
  if(V == 4){
    LDA_(0, 0); LDB_(0, 0, bfv0); LDB_(0, 1, bfv1);
    WAITL0; SBAR;
  }

  for(int rep=0; rep<3; ++rep){
    #pragma unroll 2
    for(int t=0; t<16; ++t){
      if(V == 2){
        LDA_(0, 0); LDB_(0, 0, bfv0);
        SBAR; WAITL0; SCHB; SP1; MM_(0, bfv0, 0); SP0; SBAR;
        LDB_(0, 1, bfv1);
        SBAR; WAITL0; SCHB; SP1; MM_(0, bfv1, 1); SP0; SBAR;
        LDA_(0, 1);
        SBAR; WAITL0; SCHB; SP1; MM_(1, bfv1, 1); SP0; SBAR;
        SCHB; SP1; MM_(1, bfv0, 0); SP0; SBAR;
      } else if(V == 3){
        const int bo = (t & 1) << 15;
        const int ts = (t & 15) << 6;
        SBAR; SBAR; SBAR; SBAR; SBAR; SBAR;
        STG(A , bm, bo,         ts);
        STG(Bt, bn, bo + 16384, ts);
        WV8; SBAR;
      } else { // V == 4
        SBAR; SCHB; SP1; MM_(0, bfv0, 0); SP0; SBAR;
        SBAR; SCHB; SP1; MM_(0, bfv1, 1); SP0; SBAR;
        SBAR; SCHB; SP1; MM_(1, bfv1, 1); SP0; SBAR;
        SCHB; SP1; MM_(1, bfv0, 0); SP0; SBAR;
      }
    }
  }
  WV0;
  float s0 = 0.f;
  #pragma unroll
  for(int a=0;a<8;a++)
    #pragma unroll
    for(int b=0;b<4;b++)
      s0 += acc[a][b][0] + acc[a][b][1] + acc[a][b][2] + acc[a][b][3];
  asm volatile("" :: "v"(s0));   // keep acc live (rule #17); no global writes
}

#undef STG
#undef LDA_
#undef LDB_
#undef MM_

// ============ out_gemm body: 256x128 (BK=64) 3-deep pipelined (round-2/3 structure) ==========
__device__ __forceinline__ void gemm_pipe(const u16* __restrict__ A,
                                          const u16* __restrict__ Bt,
                                          int bm, int bn,
                                          u16* __restrict__ lds,
                                          f32x4 (&acc)[4][4],
                                          int tid, int w, int quad, int cl,
                                          int wr, int wc)
{
  const int sx0 = ((quad    ) ^ (cl & 7)) << 3;
  const int sx1 = ((quad + 4) ^ (cl & 7)) << 3;
  const int arow = ((wr << 6) + cl) << 6;
  const int brow = (((wc << 6) + cl) << 6) + 16384;
  bf16x8 af[4][2], bfv[2][2];

#define STAGE128(G, gbase, dsto, kk) { \
    _Pragma("unroll") \
    for(int ii=0;ii<2;ii++){ \
      int slot_ = ii*512 + tid; int r_ = slot_ >> 3, cs_ = slot_ & 7; \
      gld16((G) + (size_t)((gbase) + r_)*1024 + (kk) + ((cs_ ^ (r_ & 7)) << 3), \
            lds + (dsto) + (ii*512 + (w << 6))*8); } }

#define LDA_(bo) { \
    _Pragma("unroll") \
    for(int m_=0;m_<4;m_++){ \
      int ro_ = (bo) + arow + (m_ << 10); \
      af[m_][0] = *(const bf16x8*)(lds + ro_ + sx0); \
      af[m_][1] = *(const bf16x8*)(lds + ro_ + sx1); } }

#define LDB_(bo, nh) { \
    _Pragma("unroll") \
    for(int j_=0;j_<2;j_++){ \
      int ro_ = (bo) + brow + (((nh)*2 + j_) << 10); \
      bfv[j_][0] = *(const bf16x8*)(lds + ro_ + sx0); \
      bfv[j_][1] = *(const bf16x8*)(lds + ro_ + sx1); } }

#define MM_(nh) { \
    _Pragma("unroll") \
    for(int m_=0;m_<4;m_++) \
      _Pragma("unroll") \
      for(int j_=0;j_<2;j_++){ \
        acc[m_][(nh)*2+j_] = MFMA(af[m_][0], bfv[j_][0], acc[m_][(nh)*2+j_]); \
        acc[m_][(nh)*2+j_] = MFMA(af[m_][1], bfv[j_][1], acc[m_][(nh)*2+j_]); } }

  STAGE128(A , bm      , 0,          0);
  STAGE128(A , bm + 128, 8192,       0);
  STAGE128(Bt, bn      , 16384,      0);
  STAGE128(A , bm      , 24576,      64);
  STAGE128(A , bm + 128, 24576+8192, 64);
  STAGE128(Bt, bn      , 24576+16384,64);
  WAITV6; SBAR;

  #pragma unroll 2
  for(int t=0;t<16;t++){
    const int c  = (t % 3) * 24576;
    const int n2 = ((t+2) % 3) * 24576;
    const int ts = ((t+2) & 15) << 6;
    LDA_(c); LDB_(c, 0);
    STAGE128(A, bm      , n2,        ts);
    STAGE128(A, bm + 128, n2 + 8192, ts);
    SBAR; WAITL0; SCHB;
    SP1; MM_(0); SP0;
    SBAR;
    LDB_(c, 1);
    STAGE128(Bt, bn, n2 + 16384, ts);
    SBAR; WAITL0; SCHB;
    SP1; MM_(1); SP0;
    WAITV6;
    SBAR;
  }
#undef STAGE128
#undef LDA_
#undef LDB_
#undef MM_
}

// ---------------- output GEMM: out[8192 x 1024] f32 = A * WoT, 256x128 3-deep pipeline -------
__global__ __launch_bounds__(512, 2)
void out_gemm_kernel(const u16* __restrict__ A, const u16* __restrict__ Bt,
                     float* __restrict__ Cf)
{
  __shared__ u16 lds[73728];
  const int tid = threadIdx.x, w = tid >> 6, lane = tid & 63;
  const int quad = lane >> 4, cl = lane & 15;
  const int wr = w >> 1, wc = w & 1;
  const int bm = blockIdx.x*256, bn = blockIdx.y*128;

  f32x4 acc[4][4];
  #pragma unroll
  for(int a=0;a<4;a++)
    #pragma unroll
    for(int b=0;b<4;b++){ f32x4 z = {0.f,0.f,0.f,0.f}; acc[a][b] = z; }

  gemm_pipe(A, Bt, bm, bn, lds, acc, tid, w, quad, cl, wr, wc);

  #pragma unroll
  for(int mf=0; mf<4; mf++)
    #pragma unroll
    for(int nf=0; nf<4; nf++)
      #pragma unroll
      for(int i=0;i<4;i++){
        int m = bm + wr*64 + mf*16 + quad*4 + i;
        int n = bn + wc*64 + nf*16 + cl;
        Cf[(size_t)m*1024 + n] = acc[mf][nf][i];
      }
}

// ---------------- attention (vis): 8 waves x 16 q-rows; grid x=bh (XCD-grouped K/V) ----------------
__global__ __launch_bounds__(512, 4)
void attn_vis_kernel(const u16* __restrict__ Q, const u16* __restrict__ Kc,
                     const u16* __restrict__ Vt, u16* __restrict__ visA,
                     float* __restrict__ rl_g)
{
  __shared__ u16 lds[17408];
  u16* Pl  = lds;
  u16* Kst = lds + 9216;
  u16* Vst = lds + 13312;
  const int tid = threadIdx.x, w = tid>>6, lane = tid&63;
  const int quad = lane>>4, cl = lane&15;
  const int bh = blockIdx.x, q0 = blockIdx.y*128;
  const u16* Qh  = Q  + (size_t)bh*65536;
  const u16* Kh  = Kc + (size_t)bh*65536;
  const u16* Vth = Vt + (size_t)bh*65536;

  #pragma unroll
  for(int i=0;i<2;i++){
    int slot = i*512 + tid;
    int c = slot >> 7, r = slot & 127;
    gld16(Qh + (size_t)(q0 + r)*64 + c*8, Pl + slot*8);
  }
  __syncthreads();
  bf16x8 qf[2];
  #pragma unroll
  for(int kk=0;kk<2;kk++)
    qf[kk] = *(const bf16x8*)(Pl + ((kk*4+quad)*128 + w*16 + cl)*8);
  __syncthreads();

  float lrun = 0.f;
  f32x4 oacc[4];
  #pragma unroll
  for(int dt=0;dt<4;dt++){ f32x4 z = {0.f,0.f,0.f,0.f}; oacc[dt] = z; }

  for(int kt=0;kt<16;kt++){
    __syncthreads();
    {
      int slot = tid;
      { int c = slot >> 6, r = slot & 63;
        gld16(Kh + (size_t)(kt*64 + r)*64 + c*8, Kst + slot*8); }
      { int d = slot >> 3, ch = slot & 7;
        gld16(Vth + (size_t)d*1024 + kt*64 + (ch^(d&7))*8, Vst + slot*8); }
    }
    __syncthreads();
    #pragma unroll
    for(int mtk=0;mtk<4;mtk++){
      f32x4 s = {0.f,0.f,0.f,0.f};
      #pragma unroll
      for(int kk=0;kk<2;kk++){
        bf16x8 ka = *(const bf16x8*)(Kst + ((kk*4+quad)*64 + mtk*16 + cl)*8);
        s = MFMA(ka, qf[kk], s);
      }
      float p0 = __builtin_amdgcn_exp2f(s[0]*LOG2E);
      float p1 = __builtin_amdgcn_exp2f(s[1]*LOG2E);
      float p2 = __builtin_amdgcn_exp2f(s[2]*LOG2E);
      float p3 = __builtin_amdgcn_exp2f(s[3]*LOG2E);
      lrun += (p0+p1)+(p2+p3);
      *(u16x4*)(Pl + (w*16 + cl)*72 + mtk*16 + quad*4) = pk4(p0,p1,p2,p3);
    }
    bf16x8 pa[2];
    #pragma unroll
    for(int kk=0;kk<2;kk++)
      pa[kk] = *(const bf16x8*)(Pl + (w*16 + cl)*72 + kk*32 + quad*8);
    #pragma unroll
    for(int dt=0;dt<4;dt++){
      int d = dt*16 + cl;
      #pragma unroll
      for(int kk=0;kk<2;kk++){
        bf16x8 vb = *(const bf16x8*)(Vst + d*64 + (((kk*4+quad)^(d&7))*8));
        oacc[dt] = MFMA(pa[kk], vb, oacc[dt]);
      }
    }
  }
  lrun += __shfl_xor(lrun, 16, 64);
  lrun += __shfl_xor(lrun, 32, 64);
  float rl = 1.f/lrun;
  if(quad == 0) rl_g[bh*1024 + q0 + w*16 + cl] = rl;
  const int b = bh >> 4, h = bh & 15;
  #pragma unroll
  for(int i=0;i<4;i++){
    float rr = __shfl(rl, quad*4 + i, 16);
    int q = q0 + w*16 + quad*4 + i;
    #pragma unroll
    for(int dt=0;dt<4;dt++)
      visA[(size_t)(b*1024 + q)*1024 + h*64 + dt*16 + cl] = f2bf(oacc[dt][i]*rr);
  }
}

// ---------------- attention (txt): 8 waves x 16 k-rows; grid x=bh; rl applied in-kernel ----------
__global__ __launch_bounds__(512, 4)
void attn_txt_kernel(const u16* __restrict__ Kc, const u16* __restrict__ Q,
                     const u16* __restrict__ V2t, const float* __restrict__ rl_g,
                     u16* __restrict__ txtA)
{
  __shared__ u16 lds[17408];
  u16* Pl  = lds;
  u16* Qst = lds + 9216;
  u16* Vst = lds + 13312;
  const int tid = threadIdx.x, w = tid>>6, lane = tid&63;
  const int quad = lane>>4, cl = lane&15;
  const int bh = blockIdx.x, k0 = blockIdx.y*128;
  const u16* Kh  = Kc  + (size_t)bh*65536;
  const u16* Qh  = Q   + (size_t)bh*65536;
  const u16* Vth = V2t + (size_t)bh*65536;

  #pragma unroll
  for(int i=0;i<2;i++){
    int slot = i*512 + tid;
    int c = slot >> 7, r = slot & 127;
    gld16(Kh + (size_t)(k0 + r)*64 + c*8, Pl + slot*8);
  }
  __syncthreads();
  bf16x8 kb[2];
  #pragma unroll
  for(int kk=0;kk<2;kk++)
    kb[kk] = *(const bf16x8*)(Pl + ((kk*4+quad)*128 + w*16 + cl)*8);
  __syncthreads();

  f32x4 oacc[4];
  #pragma unroll
  for(int dt=0;dt<4;dt++){ f32x4 z = {0.f,0.f,0.f,0.f}; oacc[dt] = z; }

  for(int qt=0;qt<16;qt++){
    __syncthreads();
    {
      int slot = tid;
      { int c = slot >> 6, r = slot & 63;
        gld16(Qh + (size_t)(qt*64 + r)*64 + c*8, Qst + slot*8); }
      { int d = slot >> 3, ch = slot & 7;
        gld16(Vth + (size_t)d*1024 + qt*64 + (ch^(d&7))*8, Vst + slot*8); }
    }
    __syncthreads();
    f32x4 rv[4];
    #pragma unroll
    for(int mtq=0;mtq<4;mtq++)
      rv[mtq] = *(const f32x4*)(rl_g + bh*1024 + qt*64 + mtq*16 + quad*4);
    #pragma unroll
    for(int mtq=0;mtq<4;mtq++){
      f32x4 s = {0.f,0.f,0.f,0.f};
      #pragma unroll
      for(int kk=0;kk<2;kk++){
        bf16x8 qa = *(const bf16x8*)(Qst + ((kk*4+quad)*64 + mtq*16 + cl)*8);
        s = MFMA(qa, kb[kk], s);
      }
      float p0 = __builtin_amdgcn_exp2f(s[0]*LOG2E)*rv[mtq][0];
      float p1 = __builtin_amdgcn_exp2f(s[1]*LOG2E)*rv[mtq][1];
      float p2 = __builtin_amdgcn_exp2f(s[2]*LOG2E)*rv[mtq][2];
      float p3 = __builtin_amdgcn_exp2f(s[3]*LOG2E)*rv[mtq][3];
      *(u16x4*)(Pl + (w*16 + cl)*72 + mtq*16 + quad*4) = pk4(p0,p1,p2,p3);
    }
    bf16x8 pa[2];
    #pragma unroll
    for(int kk=0;kk<2;kk++)
      pa[kk] = *(const bf16x8*)(Pl + (w*16 + cl)*72 + kk*32 + quad*8);
    #pragma unroll
    for(int dt=0;dt<4;dt++){
      int d = dt*16 + cl;
      #pragma unroll
      for(int kk=0;kk<2;kk++){
        bf16x8 vb = *(const bf16x8*)(Vst + d*64 + (((kk*4+quad)^(d&7))*8));
        oacc[dt] = MFMA(pa[kk], vb, oacc[dt]);
      }
    }
  }
  const int b = bh >> 4, h = bh & 15;
  #pragma unroll
  for(int i=0;i<4;i++){
    int k = k0 + w*16 + quad*4 + i;
    #pragma unroll
    for(int dt=0;dt<4;dt++)
      txtA[(size_t)(b*1024 + k)*1024 + h*64 + dt*16 + cl] = f2bf(oacc[dt][i]);
  }
}

extern "C" void kernel_launch(void* const* d_in, const int* in_sizes, int n_in,
                              void* d_out, int out_size, void* d_ws, size_t ws_size,
                              hipStream_t stream)
{
  const float* vis = (const float*)d_in[0];
  const float* txt = (const float*)d_in[1];
  const float* Wq  = (const float*)d_in[2];
  const float* Wk  = (const float*)d_in[3];
  const float* Wv  = (const float*)d_in[4];
  const float* Wo  = (const float*)d_in[5];
  float* out = (float*)d_out;

  char* ws = (char*)d_ws;
  const size_t MB = 1u << 20;
  u16* vis16 = (u16*)(ws + 0);           // later: visA
  u16* txt16 = (u16*)(ws + 8*MB);        // later: txtA (contiguous with visA for out GEMM)
  u16* Wvis  = (u16*)(ws + 16*MB);       // [WqT | WvT]
  u16* Wtxt  = (u16*)(ws + 20*MB);       // [WkT | WvT]
  u16* Qb    = (u16*)(ws + 24*MB);
  u16* Kb    = (u16*)(ws + 32*MB);
  u16* Vt    = (u16*)(ws + 40*MB);       // V^T  [b][h][d][s]  (from txt proj)
  u16* V2t   = (u16*)(ws + 48*MB);       // V2^T [b][h][d][s]  (from vis proj)
  float* rl_g = (float*)(ws + 56*MB);
  u16* WoT   = (u16*)(ws + 57*MB);
  u16* visA = vis16;  u16* txtA = txt16;

  // 1: cast both inputs + 5 weight transposes
  prep_kernel<<<9472, 256, 0, stream>>>(vis, vis16, txt, txt16,
                                        Wq, Wk, Wv, Wo,
                                        Wvis, Wvis + 1048576, Wtxt, Wtxt + 1048576, WoT);
  // 2: merged projections (round-3 known-good 43.4us), 256 blocks (1/CU)
  proj_gemm_kernel<<<dim3(16,8,2), 512, 0, stream>>>(vis16, txt16, Wvis, Wtxt,
                                                     Qb, V2t, Kb, Vt);
  // 3: attention vis (produces rl)
  attn_vis_kernel<<<dim3(64,8), 512, 0, stream>>>(Qb, Kb, Vt, visA, rl_g);
  // 4: attention txt (applies rl in-kernel)
  attn_txt_kernel<<<dim3(64,8), 512, 0, stream>>>(Kb, Qb, V2t, rl_g, txtA);
  // 5: merged output projection: M=8192 over visA||txtA (contiguous), f32 out
  out_gemm_kernel<<<dim3(32,8), 512, 0, stream>>>(visA, WoT, out);
  // --- DIAGNOSTIC PROBES (timing-only, write nothing; removed next round) ---
  proj_probe<2><<<dim3(16,8,2), 512, 0, stream>>>(vis16, txt16, Wvis, Wtxt);
  proj_probe<3><<<dim3(16,8,2), 512, 0, stream>>>(vis16, txt16, Wvis, Wtxt);
  proj_probe<4><<<dim3(16,8,2), 512, 0, stream>>>(vis16, txt16, Wvis, Wtxt);
}

// Round 7
// 300.220 us; speedup vs baseline: 1.2465x; 1.2465x over previous
//
#include <hip/hip_runtime.h>

typedef unsigned short u16;
typedef unsigned int u32;
typedef __bf16 bf16x8 __attribute__((ext_vector_type(8)));
typedef float f32x4 __attribute__((ext_vector_type(4)));
typedef u16 u16x4 __attribute__((ext_vector_type(4)));
typedef __attribute__((address_space(1))) void* as1_t;
typedef __attribute__((address_space(3))) void* as3_t;

#define LOG2E 1.4426950408889634f
#define MFMA(a,b,c) __builtin_amdgcn_mfma_f32_16x16x32_bf16(a,b,c,0,0,0)

__device__ __forceinline__ u16 f2bf(float f){
  u32 u = __float_as_uint(f);
  return (u16)((u + 0x7FFFu + ((u >> 16) & 1u)) >> 16);
}
__device__ __forceinline__ float bf2f(u16 x){
  return __uint_as_float(((u32)x) << 16);
}
#if __has_builtin(__builtin_amdgcn_cvt_pk_bf16_f32)
__device__ __forceinline__ u16x4 pk4(float a, float b, float c, float d){
  auto lo = __builtin_amdgcn_cvt_pk_bf16_f32(a,b);
  auto hi = __builtin_amdgcn_cvt_pk_bf16_f32(c,d);
  union { u16x4 v; u32 w[2]; } u;
  u.w[0] = __builtin_bit_cast(u32, lo);
  u.w[1] = __builtin_bit_cast(u32, hi);
  return u.v;
}
#else
__device__ __forceinline__ u16x4 pk4(float a, float b, float c, float d){
  u16x4 r = { f2bf(a), f2bf(b), f2bf(c), f2bf(d) };
  return r;
}
#endif
__device__ __forceinline__ void gld16(const u16* gp, u16* lp){
  __builtin_amdgcn_global_load_lds((as1_t)(u16*)gp, (as3_t)lp, 16, 0, 0);
}

#define SBAR  __builtin_amdgcn_s_barrier()
#define SP1   __builtin_amdgcn_s_setprio(1)
#define SP0   __builtin_amdgcn_s_setprio(0)
#define WV0 asm volatile("s_waitcnt vmcnt(0)" ::: "memory")
#define WV8 asm volatile("s_waitcnt vmcnt(8)" ::: "memory")

// ---------------- prep: cast both inputs + all 5 weight transposes, ONE launch ----------------
__global__ void prep_kernel(const float* __restrict__ vis, u16* __restrict__ vis16,
                            const float* __restrict__ txt, u16* __restrict__ txt16,
                            const float* __restrict__ Wq, const float* __restrict__ Wk,
                            const float* __restrict__ Wv, const float* __restrict__ Wo,
                            u16* __restrict__ T0, u16* __restrict__ T1,
                            u16* __restrict__ T2, u16* __restrict__ T3,
                            u16* __restrict__ T4){
  int bid = blockIdx.x;
  if(bid < 8192){
    const float* src = (bid < 4096) ? vis : txt;
    u16* dst = (bid < 4096) ? vis16 : txt16;
    int idx = ((bid & 4095)*256 + threadIdx.x)*4;
    float4 v = *(const float4*)(src + idx);
    *(u16x4*)(dst + idx) = pk4(v.x, v.y, v.z, v.w);
    return;
  }
  int rr = bid - 8192;
  int wi = rr >> 8, tile = rr & 255;
  const float* W; u16* WT;
  switch(wi){
    case 0: W = Wq; WT = T0; break;
    case 1: W = Wv; WT = T1; break;
    case 2: W = Wk; WT = T2; break;
    case 3: W = Wv; WT = T3; break;
    default: W = Wo; WT = T4; break;
  }
  __shared__ u16 t[64][65];
  int bn = (tile & 15)*64, bk = (tile >> 4)*64;
  int c = threadIdx.x & 63, r0 = threadIdx.x >> 6;
  #pragma unroll
  for(int j=0;j<64;j+=4){
    int r = r0 + j;
    t[r][c] = f2bf(W[(bk + r)*1024 + bn + c]);
  }
  __syncthreads();
  #pragma unroll
  for(int j=0;j<64;j+=4){
    int r = r0 + j;
    WT[(bn + r)*1024 + bk + c] = t[c][r];
  }
}

// ============ 128x128 (BK=64) 2-buf GEMM body, 4 waves, 2 BLOCKS/CU (TLP hides staging) ======
// LDS 64 KiB: buf c at c*16384 (u16): A [128][64] at +0, B [128][64] at +8192.
// Per tile: 16 ds_read_b128 + 32 MFMA per wave; compiler inserts counted lgkm waits (m97 path).
// Stage t+2 into buf c AFTER post-MFMA barrier (buffer provably free); vmcnt(8) drains t+1
// (issued one full tile earlier); never drains to 0 in-loop. 2 barrier/tile.
// XOR swizzle on GLOBAL source (involution, rule #21), linear LDS dest.
#define STG128(G, gbase, dsto, kk) { \
    _Pragma("unroll") \
    for(int ii=0;ii<4;ii++){ \
      int slot_ = ii*256 + tid; int r_ = slot_ >> 3, cs_ = slot_ & 7; \
      gld16((G) + (size_t)((gbase) + r_)*1024 + (kk) + ((cs_ ^ (r_ & 7)) << 3), \
            lds + (dsto) + (ii*256 + (w << 6))*8); } }

__device__ __forceinline__ void gemm128_pipe(const u16* __restrict__ A,
                                             const u16* __restrict__ Bt,
                                             int bm, int bn,
                                             u16* __restrict__ lds,
                                             f32x4 (&acc)[4][4],
                                             int tid, int w, int quad, int cl,
                                             int wr, int wc)
{
  const int sx0 = ((quad    ) ^ (cl & 7)) << 3;   // kc=0 16B slot (u16 units)
  const int sx1 = ((quad + 4) ^ (cl & 7)) << 3;   // kc=1
  const int arow = ((wr << 6) + cl) << 6;         // (wr*64 + cl)*64
  const int brow = (((wc << 6) + cl) << 6) + 8192;
  bf16x8 af[4][2], bfv[4][2];

  // prologue: tile0 -> buf0, tile1 -> buf1; drain tile0 (8 oldest), keep tile1 (8) in flight
  STG128(A , bm, 0,           0);
  STG128(Bt, bn, 8192,        0);
  STG128(A , bm, 16384,       64);
  STG128(Bt, bn, 16384+8192,  64);
  WV8; SBAR;

  #pragma unroll 2
  for(int t=0; t<16; ++t){
    const int c = (t & 1) << 14;       // current buffer (u16 offset: 0 / 16384)
    // ds_reads for this tile (compiler pairs them with MFMAs via counted lgkmcnt)
    #pragma unroll
    for(int m=0;m<4;m++){
      int ro = c + arow + (m << 10);
      af[m][0] = *(const bf16x8*)(lds + ro + sx0);
      af[m][1] = *(const bf16x8*)(lds + ro + sx1);
    }
    #pragma unroll
    for(int n=0;n<4;n++){
      int ro = c + brow + (n << 10);
      bfv[n][0] = *(const bf16x8*)(lds + ro + sx0);
      bfv[n][1] = *(const bf16x8*)(lds + ro + sx1);
    }
    SP1;
    #pragma unroll
    for(int m=0;m<4;m++)
      #pragma unroll
      for(int n=0;n<4;n++){
        acc[m][n] = MFMA(af[m][0], bfv[n][0], acc[m][n]);
        acc[m][n] = MFMA(af[m][1], bfv[n][1], acc[m][n]);
      }
    SP0;
    SBAR;                              // all waves' reads of buf c complete
    const int ts = ((t < 14) ? t + 2 : t) << 6;   // clamp: benign restage on last two iters
    STG128(A , bm, c,        ts);      // stage tile t+2 into freed buffer
    STG128(Bt, bn, c + 8192, ts);
    WV8;                               // drain tile t+1's 8 loads (issued 1 full tile ago)
    SBAR;                              // next tile may read buf c^1
  }
}

// ---------------- merged projection GEMM: 128x128 tiles, 2 blocks/CU ------------------------
// grid (32 m, 16 n, 2 z): bid%8 = m%8 -> A-panel sharers co-located per XCD.
// z=0: vis->[Q | V2^T], z=1: txt->[K | V^T]
__global__ __launch_bounds__(256, 2)
void proj_gemm_kernel(const u16* __restrict__ Avis, const u16* __restrict__ Atxt,
                      const u16* __restrict__ Wvis, const u16* __restrict__ Wtxt,
                      u16* __restrict__ Qb, u16* __restrict__ V2t,
                      u16* __restrict__ Kb, u16* __restrict__ Vt)
{
  const u16 *A, *Bt; u16 *Cn, *Ct;
  if(blockIdx.z == 0){ A = Avis; Bt = Wvis; Cn = Qb; Ct = V2t; }
  else               { A = Atxt; Bt = Wtxt; Cn = Kb; Ct = Vt;  }
  __shared__ u16 lds[32768];           // 64 KiB -> 2 blocks/CU
  const int tid = threadIdx.x, w = tid >> 6, lane = tid & 63;
  const int quad = lane >> 4, cl = lane & 15;
  const int wr = w >> 1, wc = w & 1;   // 2x2 waves, 64x64 per wave
  const int bm = blockIdx.x*128, bn = blockIdx.y*128;

  f32x4 acc[4][4];
  #pragma unroll
  for(int a=0;a<4;a++)
    #pragma unroll
    for(int b=0;b<4;b++){ f32x4 z = {0.f,0.f,0.f,0.f}; acc[a][b] = z; }

  gemm128_pipe(A, Bt, bm, bn, lds, acc, tid, w, quad, cl, wr, wc);

  if(bn < 1024){
    #pragma unroll
    for(int mf=0; mf<4; mf++){
      int m0 = bm + wr*64 + mf*16 + quad*4;
      #pragma unroll
      for(int nf=0; nf<4; nf++){
        int n = bn + wc*64 + nf*16 + cl;
        int h = n >> 6, d = n & 63;
        #pragma unroll
        for(int i2=0;i2<4;i2++){
          int m = m0 + i2; int b = m >> 10, s = m & 1023;
          Cn[(((size_t)(b*16 + h)*1024 + s) << 6) + d] = f2bf(acc[mf][nf][i2]);
        }
      }
    }
  } else {
    #pragma unroll
    for(int mf=0; mf<4; mf++){
      int m0 = bm + wr*64 + mf*16 + quad*4;
      int b = m0 >> 10, s = m0 & 1023;
      #pragma unroll
      for(int nf=0; nf<4; nf++){
        int nn = bn - 1024 + wc*64 + nf*16 + cl;
        int h = nn >> 6, d = nn & 63;
        *(u16x4*)(Ct + (((size_t)(b*16 + h)*64 + d) << 10) + s) =
            pk4(acc[mf][nf][0], acc[mf][nf][1], acc[mf][nf][2], acc[mf][nf][3]);
      }
    }
  }
}

// ---------------- output GEMM: out[8192 x 1024] f32 = A * WoT, 128x128, 2 blocks/CU ----------
// grid (64 m, 8 n): bid%8 = m%8 -> A-panel sharers co-located per XCD.
__global__ __launch_bounds__(256, 2)
void out_gemm_kernel(const u16* __restrict__ A, const u16* __restrict__ Bt,
                     float* __restrict__ Cf)
{
  __shared__ u16 lds[32768];
  const int tid = threadIdx.x, w = tid >> 6, lane = tid & 63;
  const int quad = lane >> 4, cl = lane & 15;
  const int wr = w >> 1, wc = w & 1;
  const int bm = blockIdx.x*128, bn = blockIdx.y*128;

  f32x4 acc[4][4];
  #pragma unroll
  for(int a=0;a<4;a++)
    #pragma unroll
    for(int b=0;b<4;b++){ f32x4 z = {0.f,0.f,0.f,0.f}; acc[a][b] = z; }

  gemm128_pipe(A, Bt, bm, bn, lds, acc, tid, w, quad, cl, wr, wc);

  #pragma unroll
  for(int mf=0; mf<4; mf++)
    #pragma unroll
    for(int nf=0; nf<4; nf++)
      #pragma unroll
      for(int i=0;i<4;i++){
        int m = bm + wr*64 + mf*16 + quad*4 + i;
        int n = bn + wc*64 + nf*16 + cl;
        Cf[(size_t)m*1024 + n] = acc[mf][nf][i];
      }
}

// ---------------- DIAGNOSTIC: staging-stream-only probe (old 256x256/1-block config) ---------
// Measures the pure global->LDS stream: 64 KiB/tile, 8 loads/thread, barrier skeleton, REPS=6.
// Readout: dispatch >=110us -> stream itself slow; <=45us or hidden -> composition-only cost.
__global__ __launch_bounds__(512, 2)
void stage_probe(const u16* __restrict__ Avis, const u16* __restrict__ Atxt,
                 const u16* __restrict__ Wvis, const u16* __restrict__ Wtxt)
{
  const u16 *A, *Bt;
  if(blockIdx.z == 0){ A = Avis; Bt = Wvis; }
  else               { A = Atxt; Bt = Wtxt; }
  __shared__ u16 lds[65536];
  const int tid = threadIdx.x, w = tid >> 6;
  const int bm = blockIdx.x*256, bn = blockIdx.y*256;
#define STGP(G, gbase, dsto, kk) { \
    _Pragma("unroll") \
    for(int ii=0;ii<4;ii++){ \
      int slot_ = ii*512 + tid; int r_ = slot_ >> 3, cs_ = slot_ & 7; \
      gld16((G) + (size_t)((gbase) + r_)*1024 + (kk) + ((cs_ ^ (r_ & 7)) << 3), \
            lds + (dsto) + (ii*512 + (w << 6))*8); } }
  for(int rep=0; rep<6; ++rep){
    #pragma unroll 2
    for(int t=0; t<16; ++t){
      const int bo = (t & 1) << 15;
      const int ts = (t & 15) << 6;
      SBAR; SBAR; SBAR; SBAR; SBAR; SBAR;
      STGP(A , bm, bo,         ts);
      STGP(Bt, bn, bo + 16384, ts);
      WV8; SBAR;
    }
  }
  WV0;
#undef STGP
}

// ---------------- attention (vis): 8 waves x 16 q-rows; grid x=bh (XCD-grouped K/V) ----------------
__global__ __launch_bounds__(512, 4)
void attn_vis_kernel(const u16* __restrict__ Q, const u16* __restrict__ Kc,
                     const u16* __restrict__ Vt, u16* __restrict__ visA,
                     float* __restrict__ rl_g)
{
  __shared__ u16 lds[17408];
  u16* Pl  = lds;
  u16* Kst = lds + 9216;
  u16* Vst = lds + 13312;
  const int tid = threadIdx.x, w = tid>>6, lane = tid&63;
  const int quad = lane>>4, cl = lane&15;
  const int bh = blockIdx.x, q0 = blockIdx.y*128;
  const u16* Qh  = Q  + (size_t)bh*65536;
  const u16* Kh  = Kc + (size_t)bh*65536;
  const u16* Vth = Vt + (size_t)bh*65536;

  #pragma unroll
  for(int i=0;i<2;i++){
    int slot = i*512 + tid;
    int c = slot >> 7, r = slot & 127;
    gld16(Qh + (size_t)(q0 + r)*64 + c*8, Pl + slot*8);
  }
  __syncthreads();
  bf16x8 qf[2];
  #pragma unroll
  for(int kk=0;kk<2;kk++)
    qf[kk] = *(const bf16x8*)(Pl + ((kk*4+quad)*128 + w*16 + cl)*8);
  __syncthreads();

  float lrun = 0.f;
  f32x4 oacc[4];
  #pragma unroll
  for(int dt=0;dt<4;dt++){ f32x4 z = {0.f,0.f,0.f,0.f}; oacc[dt] = z; }

  for(int kt=0;kt<16;kt++){
    __syncthreads();
    {
      int slot = tid;
      { int c = slot >> 6, r = slot & 63;
        gld16(Kh + (size_t)(kt*64 + r)*64 + c*8, Kst + slot*8); }
      { int d = slot >> 3, ch = slot & 7;
        gld16(Vth + (size_t)d*1024 + kt*64 + (ch^(d&7))*8, Vst + slot*8); }
    }
    __syncthreads();
    #pragma unroll
    for(int mtk=0;mtk<4;mtk++){
      f32x4 s = {0.f,0.f,0.f,0.f};
      #pragma unroll
      for(int kk=0;kk<2;kk++){
        bf16x8 ka = *(const bf16x8*)(Kst + ((kk*4+quad)*64 + mtk*16 + cl)*8);
        s = MFMA(ka, qf[kk], s);
      }
      float p0 = __builtin_amdgcn_exp2f(s[0]*LOG2E);
      float p1 = __builtin_amdgcn_exp2f(s[1]*LOG2E);
      float p2 = __builtin_amdgcn_exp2f(s[2]*LOG2E);
      float p3 = __builtin_amdgcn_exp2f(s[3]*LOG2E);
      lrun += (p0+p1)+(p2+p3);
      *(u16x4*)(Pl + (w*16 + cl)*72 + mtk*16 + quad*4) = pk4(p0,p1,p2,p3);
    }
    bf16x8 pa[2];
    #pragma unroll
    for(int kk=0;kk<2;kk++)
      pa[kk] = *(const bf16x8*)(Pl + (w*16 + cl)*72 + kk*32 + quad*8);
    #pragma unroll
    for(int dt=0;dt<4;dt++){
      int d = dt*16 + cl;
      #pragma unroll
      for(int kk=0;kk<2;kk++){
        bf16x8 vb = *(const bf16x8*)(Vst + d*64 + (((kk*4+quad)^(d&7))*8));
        oacc[dt] = MFMA(pa[kk], vb, oacc[dt]);
      }
    }
  }
  lrun += __shfl_xor(lrun, 16, 64);
  lrun += __shfl_xor(lrun, 32, 64);
  float rl = 1.f/lrun;
  if(quad == 0) rl_g[bh*1024 + q0 + w*16 + cl] = rl;
  const int b = bh >> 4, h = bh & 15;
  #pragma unroll
  for(int i=0;i<4;i++){
    float rr = __shfl(rl, quad*4 + i, 16);
    int q = q0 + w*16 + quad*4 + i;
    #pragma unroll
    for(int dt=0;dt<4;dt++)
      visA[(size_t)(b*1024 + q)*1024 + h*64 + dt*16 + cl] = f2bf(oacc[dt][i]*rr);
  }
}

// ---------------- attention (txt): 8 waves x 16 k-rows; grid x=bh; rl applied in-kernel ----------
__global__ __launch_bounds__(512, 4)
void attn_txt_kernel(const u16* __restrict__ Kc, const u16* __restrict__ Q,
                     const u16* __restrict__ V2t, const float* __restrict__ rl_g,
                     u16* __restrict__ txtA)
{
  __shared__ u16 lds[17408];
  u16* Pl  = lds;
  u16* Qst = lds + 9216;
  u16* Vst = lds + 13312;
  const int tid = threadIdx.x, w = tid>>6, lane = tid&63;
  const int quad = lane>>4, cl = lane&15;
  const int bh = blockIdx.x, k0 = blockIdx.y*128;
  const u16* Kh  = Kc  + (size_t)bh*65536;
  const u16* Qh  = Q   + (size_t)bh*65536;
  const u16* Vth = V2t + (size_t)bh*65536;

  #pragma unroll
  for(int i=0;i<2;i++){
    int slot = i*512 + tid;
    int c = slot >> 7, r = slot & 127;
    gld16(Kh + (size_t)(k0 + r)*64 + c*8, Pl + slot*8);
  }
  __syncthreads();
  bf16x8 kb[2];
  #pragma unroll
  for(int kk=0;kk<2;kk++)
    kb[kk] = *(const bf16x8*)(Pl + ((kk*4+quad)*128 + w*16 + cl)*8);
  __syncthreads();

  f32x4 oacc[4];
  #pragma unroll
  for(int dt=0;dt<4;dt++){ f32x4 z = {0.f,0.f,0.f,0.f}; oacc[dt] = z; }

  for(int qt=0;qt<16;qt++){
    __syncthreads();
    {
      int slot = tid;
      { int c = slot >> 6, r = slot & 63;
        gld16(Qh + (size_t)(qt*64 + r)*64 + c*8, Qst + slot*8); }
      { int d = slot >> 3, ch = slot & 7;
        gld16(Vth + (size_t)d*1024 + qt*64 + (ch^(d&7))*8, Vst + slot*8); }
    }
    __syncthreads();
    f32x4 rv[4];
    #pragma unroll
    for(int mtq=0;mtq<4;mtq++)
      rv[mtq] = *(const f32x4*)(rl_g + bh*1024 + qt*64 + mtq*16 + quad*4);
    #pragma unroll
    for(int mtq=0;mtq<4;mtq++){
      f32x4 s = {0.f,0.f,0.f,0.f};
      #pragma unroll
      for(int kk=0;kk<2;kk++){
        bf16x8 qa = *(const bf16x8*)(Qst + ((kk*4+quad)*64 + mtq*16 + cl)*8);
        s = MFMA(qa, kb[kk], s);
      }
      float p0 = __builtin_amdgcn_exp2f(s[0]*LOG2E)*rv[mtq][0];
      float p1 = __builtin_amdgcn_exp2f(s[1]*LOG2E)*rv[mtq][1];
      float p2 = __builtin_amdgcn_exp2f(s[2]*LOG2E)*rv[mtq][2];
      float p3 = __builtin_amdgcn_exp2f(s[3]*LOG2E)*rv[mtq][3];
      *(u16x4*)(Pl + (w*16 + cl)*72 + mtq*16 + quad*4) = pk4(p0,p1,p2,p3);
    }
    bf16x8 pa[2];
    #pragma unroll
    for(int kk=0;kk<2;kk++)
      pa[kk] = *(const bf16x8*)(Pl + (w*16 + cl)*72 + kk*32 + quad*8);
    #pragma unroll
    for(int dt=0;dt<4;dt++){
      int d = dt*16 + cl;
      #pragma unroll
      for(int kk=0;kk<2;kk++){
        bf16x8 vb = *(const bf16x8*)(Vst + d*64 + (((kk*4+quad)^(d&7))*8));
        oacc[dt] = MFMA(pa[kk], vb, oacc[dt]);
      }
    }
  }
  const int b = bh >> 4, h = bh & 15;
  #pragma unroll
  for(int i=0;i<4;i++){
    int k = k0 + w*16 + quad*4 + i;
    #pragma unroll
    for(int dt=0;dt<4;dt++)
      txtA[(size_t)(b*1024 + k)*1024 + h*64 + dt*16 + cl] = f2bf(oacc[dt][i]);
  }
}

extern "C" void kernel_launch(void* const* d_in, const int* in_sizes, int n_in,
                              void* d_out, int out_size, void* d_ws, size_t ws_size,
                              hipStream_t stream)
{
  const float* vis = (const float*)d_in[0];
  const float* txt = (const float*)d_in[1];
  const float* Wq  = (const float*)d_in[2];
  const float* Wk  = (const float*)d_in[3];
  const float* Wv  = (const float*)d_in[4];
  const float* Wo  = (const float*)d_in[5];
  float* out = (float*)d_out;

  char* ws = (char*)d_ws;
  const size_t MB = 1u << 20;
  u16* vis16 = (u16*)(ws + 0);           // later: visA
  u16* txt16 = (u16*)(ws + 8*MB);        // later: txtA (contiguous with visA for out GEMM)
  u16* Wvis  = (u16*)(ws + 16*MB);       // [WqT | WvT]
  u16* Wtxt  = (u16*)(ws + 20*MB);       // [WkT | WvT]
  u16* Qb    = (u16*)(ws + 24*MB);
  u16* Kb    = (u16*)(ws + 32*MB);
  u16* Vt    = (u16*)(ws + 40*MB);       // V^T  [b][h][d][s]  (from txt proj)
  u16* V2t   = (u16*)(ws + 48*MB);       // V2^T [b][h][d][s]  (from vis proj)
  float* rl_g = (float*)(ws + 56*MB);
  u16* WoT   = (u16*)(ws + 57*MB);
  u16* visA = vis16;  u16* txtA = txt16;

  // 1: cast both inputs + 5 weight transposes
  prep_kernel<<<9472, 256, 0, stream>>>(vis, vis16, txt, txt16,
                                        Wq, Wk, Wv, Wo,
                                        Wvis, Wvis + 1048576, Wtxt, Wtxt + 1048576, WoT);
  // 2: merged projections, 128x128 tiles, 2 blocks/CU; grid m-major for XCD A-reuse
  proj_gemm_kernel<<<dim3(32,16,2), 256, 0, stream>>>(vis16, txt16, Wvis, Wtxt,
                                                      Qb, V2t, Kb, Vt);
  // 3: attention vis (produces rl)
  attn_vis_kernel<<<dim3(64,8), 512, 0, stream>>>(Qb, Kb, Vt, visA, rl_g);
  // 4: attention txt (applies rl in-kernel)
  attn_txt_kernel<<<dim3(64,8), 512, 0, stream>>>(Kb, Qb, V2t, rl_g, txtA);
  // 5: merged output projection: M=8192 over visA||txtA (contiguous), f32 out
  out_gemm_kernel<<<dim3(64,8), 256, 0, stream>>>(visA, WoT, out);
  // --- DIAGNOSTIC: staging-stream probe (timing-only; removed next round) ---
  stage_probe<<<dim3(16,8,2), 512, 0, stream>>>(vis16, txt16, Wvis, Wtxt);
}

// Round 8
// 218.318 us; speedup vs baseline: 1.7141x; 1.3751x over previous
//
#include <hip/hip_runtime.h>

typedef unsigned short u16;
typedef unsigned int u32;
typedef __bf16 bf16x8 __attribute__((ext_vector_type(8)));
typedef float f32x4 __attribute__((ext_vector_type(4)));
typedef u16 u16x4 __attribute__((ext_vector_type(4)));
typedef __attribute__((address_space(1))) void* as1_t;
typedef __attribute__((address_space(3))) void* as3_t;

#define LOG2E 1.4426950408889634f
#define MFMA(a,b,c) __builtin_amdgcn_mfma_f32_16x16x32_bf16(a,b,c,0,0,0)

__device__ __forceinline__ u16 f2bf(float f){
  u32 u = __float_as_uint(f);
  return (u16)((u + 0x7FFFu + ((u >> 16) & 1u)) >> 16);
}
__device__ __forceinline__ float bf2f(u16 x){
  return __uint_as_float(((u32)x) << 16);
}
#if __has_builtin(__builtin_amdgcn_cvt_pk_bf16_f32)
__device__ __forceinline__ u16x4 pk4(float a, float b, float c, float d){
  auto lo = __builtin_amdgcn_cvt_pk_bf16_f32(a,b);
  auto hi = __builtin_amdgcn_cvt_pk_bf16_f32(c,d);
  union { u16x4 v; u32 w[2]; } u;
  u.w[0] = __builtin_bit_cast(u32, lo);
  u.w[1] = __builtin_bit_cast(u32, hi);
  return u.v;
}
#else
__device__ __forceinline__ u16x4 pk4(float a, float b, float c, float d){
  u16x4 r = { f2bf(a), f2bf(b), f2bf(c), f2bf(d) };
  return r;
}
#endif
__device__ __forceinline__ void gld16(const u16* gp, u16* lp){
  __builtin_amdgcn_global_load_lds((as1_t)(u16*)gp, (as3_t)lp, 16, 0, 0);
}

#define SBAR  __builtin_amdgcn_s_barrier()
#define SCHB  __builtin_amdgcn_sched_barrier(0)
#define SP1   __builtin_amdgcn_s_setprio(1)
#define SP0   __builtin_amdgcn_s_setprio(0)
#define WAITL0 asm volatile("s_waitcnt lgkmcnt(0)" ::: "memory")
#define WAITV6 asm volatile("s_waitcnt vmcnt(6)" ::: "memory")
#define WV8 asm volatile("s_waitcnt vmcnt(8)" ::: "memory")

// ---------------- prep: cast both inputs + all 5 weight transposes, ONE launch ----------------
__global__ void prep_kernel(const float* __restrict__ vis, u16* __restrict__ vis16,
                            const float* __restrict__ txt, u16* __restrict__ txt16,
                            const float* __restrict__ Wq, const float* __restrict__ Wk,
                            const float* __restrict__ Wv, const float* __restrict__ Wo,
                            u16* __restrict__ T0, u16* __restrict__ T1,
                            u16* __restrict__ T2, u16* __restrict__ T3,
                            u16* __restrict__ T4){
  int bid = blockIdx.x;
  if(bid < 8192){
    const float* src = (bid < 4096) ? vis : txt;
    u16* dst = (bid < 4096) ? vis16 : txt16;
    int idx = ((bid & 4095)*256 + threadIdx.x)*4;
    float4 v = *(const float4*)(src + idx);
    *(u16x4*)(dst + idx) = pk4(v.x, v.y, v.z, v.w);
    return;
  }
  int rr = bid - 8192;
  int wi = rr >> 8, tile = rr & 255;
  const float* W; u16* WT;
  switch(wi){
    case 0: W = Wq; WT = T0; break;
    case 1: W = Wv; WT = T1; break;
    case 2: W = Wk; WT = T2; break;
    case 3: W = Wv; WT = T3; break;
    default: W = Wo; WT = T4; break;
  }
  __shared__ u16 t[64][65];
  int bn = (tile & 15)*64, bk = (tile >> 4)*64;
  int c = threadIdx.x & 63, r0 = threadIdx.x >> 6;
  #pragma unroll
  for(int j=0;j<64;j+=4){
    int r = r0 + j;
    t[r][c] = f2bf(W[(bk + r)*1024 + bn + c]);
  }
  __syncthreads();
  #pragma unroll
  for(int j=0;j<64;j+=4){
    int r = r0 + j;
    WT[(bn + r)*1024 + bk + c] = t[c][r];
  }
}

// ======== proj macros (round-3 structure, 256x256, BK=64, 8 waves 2Mx4N) =====================
#define STG(G, gbase, dsto, kk) { \
    _Pragma("unroll") \
    for(int ii=0;ii<4;ii++){ \
      int slot_ = ii*512 + tid; int r_ = slot_ >> 3, cs_ = slot_ & 7; \
      gld16((G) + (size_t)((gbase) + r_)*1024 + (kk) + ((cs_ ^ (r_ & 7)) << 3), \
            lds + (dsto) + (ii*512 + (w << 6))*8); } }

#define LDA_(bo, mh) { \
    _Pragma("unroll") \
    for(int q_=0;q_<4;q_++){ \
      int ro_ = (bo) + arow + (((mh)*4 + q_) << 10); \
      af[q_][0] = *(const bf16x8*)(lds + ro_ + sx0); \
      af[q_][1] = *(const bf16x8*)(lds + ro_ + sx1); } }

#define LDB_(bo, nh, bfv) { \
    _Pragma("unroll") \
    for(int j_=0;j_<2;j_++){ \
      int ro_ = (bo) + brow + (((nh)*2 + j_) << 10); \
      bfv[j_][0] = *(const bf16x8*)(lds + ro_ + sx0); \
      bfv[j_][1] = *(const bf16x8*)(lds + ro_ + sx1); } }

// normal product: acc[m-frag][n-frag], D = A x B
#define MM_N(mh, bfv, nh) { \
    _Pragma("unroll") \
    for(int q_=0;q_<4;q_++) \
      _Pragma("unroll") \
      for(int j_=0;j_<2;j_++){ \
        int ai_ = ((mh)*4+q_)*4 + (nh)*2+j_; \
        acc[ai_] = MFMA(af[q_][0], bfv[j_][0], acc[ai_]); \
        acc[ai_] = MFMA(af[q_][1], bfv[j_][1], acc[ai_]); } }

// swapped product: acc[n-frag][m-frag] = C^T (valid: A/B fragments share lane->(idx,k) map,
// same trick the attn kernels use). Lanes then own consecutive s for the V^T store.
#define MM_T(mh, bfv, nh) { \
    _Pragma("unroll") \
    for(int q_=0;q_<4;q_++) \
      _Pragma("unroll") \
      for(int j_=0;j_<2;j_++){ \
        int ai_ = ((nh)*2+j_)*8 + (mh)*4+q_; \
        acc[ai_] = MFMA(bfv[j_][0], af[q_][0], acc[ai_]); \
        acc[ai_] = MFMA(bfv[j_][1], af[q_][1], acc[ai_]); } }

#define TILE_BODY(bufo, ts, MM) { \
    LDA_(bufo, 0); LDB_(bufo, 0, bfv0); \
    SBAR; WAITL0; SCHB; SP1; MM(0, bfv0, 0); SP0; SBAR; \
    LDB_(bufo, 1, bfv1); \
    SBAR; WAITL0; SCHB; SP1; MM(0, bfv1, 1); SP0; SBAR; \
    LDA_(bufo, 1); \
    SBAR; WAITL0; SCHB; SP1; MM(1, bfv1, 1); SP0; SBAR; \
    STG(A , bm, (bufo)        , ts); \
    STG(Bt, bn, (bufo) + 16384, ts); \
    SCHB; SP1; MM(1, bfv0, 0); SP0; \
    WV8; SBAR; }

// ---------------- merged projection GEMM (round-3 K-loop + coalesced V^T epilogue) -----------
// grid (16 m, 8 n, 2 z): bid%8 = m%8 -> A-panel sharers co-located per XCD.
// bn<1024 -> Cn [b][h][s][d] (normal acc); bn>=1024 -> Ct [b][h][d][s] via SWAPPED acc (32B runs)
__global__ __launch_bounds__(512, 2)
void proj_gemm_kernel(const u16* __restrict__ Avis, const u16* __restrict__ Atxt,
                      const u16* __restrict__ Wvis, const u16* __restrict__ Wtxt,
                      u16* __restrict__ Qb, u16* __restrict__ V2t,
                      u16* __restrict__ Kb, u16* __restrict__ Vt)
{
  const u16 *A, *Bt; u16 *Cn, *Ct;
  if(blockIdx.z == 0){ A = Avis; Bt = Wvis; Cn = Qb; Ct = V2t; }
  else               { A = Atxt; Bt = Wtxt; Cn = Kb; Ct = Vt;  }
  __shared__ u16 lds[65536];
  const int tid = threadIdx.x, w = tid >> 6, lane = tid & 63;
  const int quad = lane >> 4, cl = lane & 15;
  const int wr = w >> 2, wc = w & 3;
  const int bm = blockIdx.x*256, bn = blockIdx.y*256;
  const int sx0 = ((quad    ) ^ (cl & 7)) << 3;
  const int sx1 = ((quad + 4) ^ (cl & 7)) << 3;
  const int arow = ((wr << 7) + cl) << 6;
  const int brow = (((wc << 6) + cl) << 6) + 16384;

  f32x4 acc[32];
  #pragma unroll
  for(int a=0;a<32;a++){ f32x4 z = {0.f,0.f,0.f,0.f}; acc[a] = z; }
  bf16x8 af[4][2], bfv0[2][2], bfv1[2][2];

  // prologue: tile0 -> buf0, tile1 -> buf1; drain tile0 (8 oldest), keep tile1 in flight
  STG(A , bm, 0,     0);  STG(Bt, bn, 16384, 0);
  STG(A , bm, 32768, 64); STG(Bt, bn, 32768+16384, 64);
  WV8; SBAR;

  if(bn < 1024){
    for(int tt=0; tt<8; tt++){
      const int t0 = 2*tt;
      TILE_BODY(0,     ((t0+2)&15) << 6, MM_N);
      TILE_BODY(32768, ((t0+3)&15) << 6, MM_N);
    }
    // epilogue: [b][h][s][d], lanes -> consecutive d (32B runs)
    #pragma unroll
    for(int mf=0; mf<8; mf++){
      int m0 = bm + wr*128 + mf*16 + quad*4;
      #pragma unroll
      for(int nf=0; nf<4; nf++){
        int n = bn + wc*64 + nf*16 + cl;
        int h = n >> 6, d = n & 63;
        #pragma unroll
        for(int i2=0;i2<4;i2++){
          int m = m0 + i2; int b = m >> 10, s = m & 1023;
          Cn[(((size_t)(b*16 + h)*1024 + s) << 6) + d] = f2bf(acc[mf*4+nf][i2]);
        }
      }
    }
  } else {
    for(int tt=0; tt<8; tt++){
      const int t0 = 2*tt;
      TILE_BODY(0,     ((t0+2)&15) << 6, MM_T);
      TILE_BODY(32768, ((t0+3)&15) << 6, MM_T);
    }
    // epilogue: [b][h][d][s] with acc^T: lanes -> consecutive s (32B runs, was 8B scattered)
    const int bT = bm >> 10;
    const int sbase = (bm & 1023) + wr*128;
    #pragma unroll
    for(int nf=0; nf<4; nf++){
      #pragma unroll
      for(int i2=0;i2<4;i2++){
        int nn = (bn - 1024) + wc*64 + nf*16 + quad*4 + i2;
        int h = nn >> 6, d = nn & 63;
        u16* rowp = Ct + ((size_t)(bT*16 + h)*64 + d)*1024;
        #pragma unroll
        for(int mf=0; mf<8; mf++)
          rowp[sbase + mf*16 + cl] = f2bf(acc[nf*8+mf][i2]);
      }
    }
  }
}

#undef STG
#undef LDA_
#undef LDB_
#undef MM_N
#undef MM_T
#undef TILE_BODY

// ============ out_gemm body: 256x128 (BK=64) 3-deep pipelined (round-2/3 structure) ==========
__device__ __forceinline__ void gemm_pipe(const u16* __restrict__ A,
                                          const u16* __restrict__ Bt,
                                          int bm, int bn,
                                          u16* __restrict__ lds,
                                          f32x4 (&acc)[4][4],
                                          int tid, int w, int quad, int cl,
                                          int wr, int wc)
{
  const int sx0 = ((quad    ) ^ (cl & 7)) << 3;
  const int sx1 = ((quad + 4) ^ (cl & 7)) << 3;
  const int arow = ((wr << 6) + cl) << 6;
  const int brow = (((wc << 6) + cl) << 6) + 16384;
  bf16x8 af[4][2], bfv[2][2];

#define STAGE128(G, gbase, dsto, kk) { \
    _Pragma("unroll") \
    for(int ii=0;ii<2;ii++){ \
      int slot_ = ii*512 + tid; int r_ = slot_ >> 3, cs_ = slot_ & 7; \
      gld16((G) + (size_t)((gbase) + r_)*1024 + (kk) + ((cs_ ^ (r_ & 7)) << 3), \
            lds + (dsto) + (ii*512 + (w << 6))*8); } }

#define LDA_(bo) { \
    _Pragma("unroll") \
    for(int m_=0;m_<4;m_++){ \
      int ro_ = (bo) + arow + (m_ << 10); \
      af[m_][0] = *(const bf16x8*)(lds + ro_ + sx0); \
      af[m_][1] = *(const bf16x8*)(lds + ro_ + sx1); } }

#define LDB_(bo, nh) { \
    _Pragma("unroll") \
    for(int j_=0;j_<2;j_++){ \
      int ro_ = (bo) + brow + (((nh)*2 + j_) << 10); \
      bfv[j_][0] = *(const bf16x8*)(lds + ro_ + sx0); \
      bfv[j_][1] = *(const bf16x8*)(lds + ro_ + sx1); } }

#define MM_(nh) { \
    _Pragma("unroll") \
    for(int m_=0;m_<4;m_++) \
      _Pragma("unroll") \
      for(int j_=0;j_<2;j_++){ \
        acc[m_][(nh)*2+j_] = MFMA(af[m_][0], bfv[j_][0], acc[m_][(nh)*2+j_]); \
        acc[m_][(nh)*2+j_] = MFMA(af[m_][1], bfv[j_][1], acc[m_][(nh)*2+j_]); } }

  STAGE128(A , bm      , 0,          0);
  STAGE128(A , bm + 128, 8192,       0);
  STAGE128(Bt, bn      , 16384,      0);
  STAGE128(A , bm      , 24576,      64);
  STAGE128(A , bm + 128, 24576+8192, 64);
  STAGE128(Bt, bn      , 24576+16384,64);
  WAITV6; SBAR;

  #pragma unroll 2
  for(int t=0;t<16;t++){
    const int c  = (t % 3) * 24576;
    const int n2 = ((t+2) % 3) * 24576;
    const int ts = ((t+2) & 15) << 6;
    LDA_(c); LDB_(c, 0);
    STAGE128(A, bm      , n2,        ts);
    STAGE128(A, bm + 128, n2 + 8192, ts);
    SBAR; WAITL0; SCHB;
    SP1; MM_(0); SP0;
    SBAR;
    LDB_(c, 1);
    STAGE128(Bt, bn, n2 + 16384, ts);
    SBAR; WAITL0; SCHB;
    SP1; MM_(1); SP0;
    WAITV6;
    SBAR;
  }
#undef STAGE128
#undef LDA_
#undef LDB_
#undef MM_
}

// ---------------- output GEMM: out[8192 x 1024] f32 = A * WoT, 256x128 3-deep pipeline -------
// grid (32 m, 8 n): bid%8 = m%8 -> A-panel sharers co-located per XCD.
__global__ __launch_bounds__(512, 2)
void out_gemm_kernel(const u16* __restrict__ A, const u16* __restrict__ Bt,
                     float* __restrict__ Cf)
{
  __shared__ u16 lds[73728];
  const int tid = threadIdx.x, w = tid >> 6, lane = tid & 63;
  const int quad = lane >> 4, cl = lane & 15;
  const int wr = w >> 1, wc = w & 1;
  const int bm = blockIdx.x*256, bn = blockIdx.y*128;

  f32x4 acc[4][4];
  #pragma unroll
  for(int a=0;a<4;a++)
    #pragma unroll
    for(int b=0;b<4;b++){ f32x4 z = {0.f,0.f,0.f,0.f}; acc[a][b] = z; }

  gemm_pipe(A, Bt, bm, bn, lds, acc, tid, w, quad, cl, wr, wc);

  #pragma unroll
  for(int mf=0; mf<4; mf++)
    #pragma unroll
    for(int nf=0; nf<4; nf++)
      #pragma unroll
      for(int i=0;i<4;i++){
        int m = bm + wr*64 + mf*16 + quad*4 + i;
        int n = bn + wc*64 + nf*16 + cl;
        Cf[(size_t)m*1024 + n] = acc[mf][nf][i];
      }
}

// ---------------- attention (vis): 8 waves x 16 q-rows; grid x=bh (XCD-grouped K/V) ----------------
__global__ __launch_bounds__(512, 4)
void attn_vis_kernel(const u16* __restrict__ Q, const u16* __restrict__ Kc,
                     const u16* __restrict__ Vt, u16* __restrict__ visA,
                     float* __restrict__ rl_g)
{
  __shared__ u16 lds[17408];
  u16* Pl  = lds;
  u16* Kst = lds + 9216;
  u16* Vst = lds + 13312;
  const int tid = threadIdx.x, w = tid>>6, lane = tid&63;
  const int quad = lane>>4, cl = lane&15;
  const int bh = blockIdx.x, q0 = blockIdx.y*128;
  const u16* Qh  = Q  + (size_t)bh*65536;
  const u16* Kh  = Kc + (size_t)bh*65536;
  const u16* Vth = Vt + (size_t)bh*65536;

  #pragma unroll
  for(int i=0;i<2;i++){
    int slot = i*512 + tid;
    int c = slot >> 7, r = slot & 127;
    gld16(Qh + (size_t)(q0 + r)*64 + c*8, Pl + slot*8);
  }
  __syncthreads();
  bf16x8 qf[2];
  #pragma unroll
  for(int kk=0;kk<2;kk++)
    qf[kk] = *(const bf16x8*)(Pl + ((kk*4+quad)*128 + w*16 + cl)*8);
  __syncthreads();

  float lrun = 0.f;
  f32x4 oacc[4];
  #pragma unroll
  for(int dt=0;dt<4;dt++){ f32x4 z = {0.f,0.f,0.f,0.f}; oacc[dt] = z; }

  for(int kt=0;kt<16;kt++){
    __syncthreads();
    {
      int slot = tid;
      { int c = slot >> 6, r = slot & 63;
        gld16(Kh + (size_t)(kt*64 + r)*64 + c*8, Kst + slot*8); }
      { int d = slot >> 3, ch = slot & 7;
        gld16(Vth + (size_t)d*1024 + kt*64 + (ch^(d&7))*8, Vst + slot*8); }
    }
    __syncthreads();
    #pragma unroll
    for(int mtk=0;mtk<4;mtk++){
      f32x4 s = {0.f,0.f,0.f,0.f};
      #pragma unroll
      for(int kk=0;kk<2;kk++){
        bf16x8 ka = *(const bf16x8*)(Kst + ((kk*4+quad)*64 + mtk*16 + cl)*8);
        s = MFMA(ka, qf[kk], s);
      }
      float p0 = __builtin_amdgcn_exp2f(s[0]*LOG2E);
      float p1 = __builtin_amdgcn_exp2f(s[1]*LOG2E);
      float p2 = __builtin_amdgcn_exp2f(s[2]*LOG2E);
      float p3 = __builtin_amdgcn_exp2f(s[3]*LOG2E);
      lrun += (p0+p1)+(p2+p3);
      *(u16x4*)(Pl + (w*16 + cl)*72 + mtk*16 + quad*4) = pk4(p0,p1,p2,p3);
    }
    bf16x8 pa[2];
    #pragma unroll
    for(int kk=0;kk<2;kk++)
      pa[kk] = *(const bf16x8*)(Pl + (w*16 + cl)*72 + kk*32 + quad*8);
    #pragma unroll
    for(int dt=0;dt<4;dt++){
      int d = dt*16 + cl;
      #pragma unroll
      for(int kk=0;kk<2;kk++){
        bf16x8 vb = *(const bf16x8*)(Vst + d*64 + (((kk*4+quad)^(d&7))*8));
        oacc[dt] = MFMA(pa[kk], vb, oacc[dt]);
      }
    }
  }
  lrun += __shfl_xor(lrun, 16, 64);
  lrun += __shfl_xor(lrun, 32, 64);
  float rl = 1.f/lrun;
  if(quad == 0) rl_g[bh*1024 + q0 + w*16 + cl] = rl;
  const int b = bh >> 4, h = bh & 15;
  #pragma unroll
  for(int i=0;i<4;i++){
    float rr = __shfl(rl, quad*4 + i, 16);
    int q = q0 + w*16 + quad*4 + i;
    #pragma unroll
    for(int dt=0;dt<4;dt++)
      visA[(size_t)(b*1024 + q)*1024 + h*64 + dt*16 + cl] = f2bf(oacc[dt][i]*rr);
  }
}

// ---------------- attention (txt): 8 waves x 16 k-rows; grid x=bh; rl applied in-kernel ----------
__global__ __launch_bounds__(512, 4)
void attn_txt_kernel(const u16* __restrict__ Kc, const u16* __restrict__ Q,
                     const u16* __restrict__ V2t, const float* __restrict__ rl_g,
                     u16* __restrict__ txtA)
{
  __shared__ u16 lds[17408];
  u16* Pl  = lds;
  u16* Qst = lds + 9216;
  u16* Vst = lds + 13312;
  const int tid = threadIdx.x, w = tid>>6, lane = tid&63;
  const int quad = lane>>4, cl = lane&15;
  const int bh = blockIdx.x, k0 = blockIdx.y*128;
  const u16* Kh  = Kc  + (size_t)bh*65536;
  const u16* Qh  = Q   + (size_t)bh*65536;
  const u16* Vth = V2t + (size_t)bh*65536;

  #pragma unroll
  for(int i=0;i<2;i++){
    int slot = i*512 + tid;
    int c = slot >> 7, r = slot & 127;
    gld16(Kh + (size_t)(k0 + r)*64 + c*8, Pl + slot*8);
  }
  __syncthreads();
  bf16x8 kb[2];
  #pragma unroll
  for(int kk=0;kk<2;kk++)
    kb[kk] = *(const bf16x8*)(Pl + ((kk*4+quad)*128 + w*16 + cl)*8);
  __syncthreads();

  f32x4 oacc[4];
  #pragma unroll
  for(int dt=0;dt<4;dt++){ f32x4 z = {0.f,0.f,0.f,0.f}; oacc[dt] = z; }

  for(int qt=0;qt<16;qt++){
    __syncthreads();
    {
      int slot = tid;
      { int c = slot >> 6, r = slot & 63;
        gld16(Qh + (size_t)(qt*64 + r)*64 + c*8, Qst + slot*8); }
      { int d = slot >> 3, ch = slot & 7;
        gld16(Vth + (size_t)d*1024 + qt*64 + (ch^(d&7))*8, Vst + slot*8); }
    }
    __syncthreads();
    f32x4 rv[4];
    #pragma unroll
    for(int mtq=0;mtq<4;mtq++)
      rv[mtq] = *(const f32x4*)(rl_g + bh*1024 + qt*64 + mtq*16 + quad*4);
    #pragma unroll
    for(int mtq=0;mtq<4;mtq++){
      f32x4 s = {0.f,0.f,0.f,0.f};
      #pragma unroll
      for(int kk=0;kk<2;kk++){
        bf16x8 qa = *(const bf16x8*)(Qst + ((kk*4+quad)*64 + mtq*16 + cl)*8);
        s = MFMA(qa, kb[kk], s);
      }
      float p0 = __builtin_amdgcn_exp2f(s[0]*LOG2E)*rv[mtq][0];
      float p1 = __builtin_amdgcn_exp2f(s[1]*LOG2E)*rv[mtq][1];
      float p2 = __builtin_amdgcn_exp2f(s[2]*LOG2E)*rv[mtq][2];
      float p3 = __builtin_amdgcn_exp2f(s[3]*LOG2E)*rv[mtq][3];
      *(u16x4*)(Pl + (w*16 + cl)*72 + mtq*16 + quad*4) = pk4(p0,p1,p2,p3);
    }
    bf16x8 pa[2];
    #pragma unroll
    for(int kk=0;kk<2;kk++)
      pa[kk] = *(const bf16x8*)(Pl + (w*16 + cl)*72 + kk*32 + quad*8);
    #pragma unroll
    for(int dt=0;dt<4;dt++){
      int d = dt*16 + cl;
      #pragma unroll
      for(int kk=0;kk<2;kk++){
        bf16x8 vb = *(const bf16x8*)(Vst + d*64 + (((kk*4+quad)^(d&7))*8));
        oacc[dt] = MFMA(pa[kk], vb, oacc[dt]);
      }
    }
  }
  const int b = bh >> 4, h = bh & 15;
  #pragma unroll
  for(int i=0;i<4;i++){
    int k = k0 + w*16 + quad*4 + i;
    #pragma unroll
    for(int dt=0;dt<4;dt++)
      txtA[(size_t)(b*1024 + k)*1024 + h*64 + dt*16 + cl] = f2bf(oacc[dt][i]);
  }
}

extern "C" void kernel_launch(void* const* d_in, const int* in_sizes, int n_in,
                              void* d_out, int out_size, void* d_ws, size_t ws_size,
                              hipStream_t stream)
{
  const float* vis = (const float*)d_in[0];
  const float* txt = (const float*)d_in[1];
  const float* Wq  = (const float*)d_in[2];
  const float* Wk  = (const float*)d_in[3];
  const float* Wv  = (const float*)d_in[4];
  const float* Wo  = (const float*)d_in[5];
  float* out = (float*)d_out;

  char* ws = (char*)d_ws;
  const size_t MB = 1u << 20;
  u16* vis16 = (u16*)(ws + 0);           // later: visA
  u16* txt16 = (u16*)(ws + 8*MB);        // later: txtA (contiguous with visA for out GEMM)
  u16* Wvis  = (u16*)(ws + 16*MB);       // [WqT | WvT]
  u16* Wtxt  = (u16*)(ws + 20*MB);       // [WkT | WvT]
  u16* Qb    = (u16*)(ws + 24*MB);
  u16* Kb    = (u16*)(ws + 32*MB);
  u16* Vt    = (u16*)(ws + 40*MB);       // V^T  [b][h][d][s]  (from txt proj)
  u16* V2t   = (u16*)(ws + 48*MB);       // V2^T [b][h][d][s]  (from vis proj)
  float* rl_g = (float*)(ws + 56*MB);
  u16* WoT   = (u16*)(ws + 57*MB);
  u16* visA = vis16;  u16* txtA = txt16;

  // 1: cast both inputs + 5 weight transposes
  prep_kernel<<<9472, 256, 0, stream>>>(vis, vis16, txt, txt16,
                                        Wq, Wk, Wv, Wo,
                                        Wvis, Wvis + 1048576, Wtxt, Wtxt + 1048576, WoT);
  // 2: merged projections (round-3 K-loop + coalesced V^T epilogue), 256 blocks (1/CU)
  proj_gemm_kernel<<<dim3(16,8,2), 512, 0, stream>>>(vis16, txt16, Wvis, Wtxt,
                                                     Qb, V2t, Kb, Vt);
  // 3: attention vis (produces rl)
  attn_vis_kernel<<<dim3(64,8), 512, 0, stream>>>(Qb, Kb, Vt, visA, rl_g);
  // 4: attention txt (applies rl in-kernel)
  attn_txt_kernel<<<dim3(64,8), 512, 0, stream>>>(Kb, Qb, V2t, rl_g, txtA);
  // 5: merged output projection: M=8192 over visA||txtA (contiguous), f32 out
  out_gemm_kernel<<<dim3(32,8), 512, 0, stream>>>(visA, WoT, out);
}

// Round 9
// 214.870 us; speedup vs baseline: 1.7416x; 1.0160x over previous
//
#include <hip/hip_runtime.h>

typedef unsigned short u16;
typedef unsigned int u32;
typedef __bf16 bf16x8 __attribute__((ext_vector_type(8)));
typedef float f32x4 __attribute__((ext_vector_type(4)));
typedef u16 u16x4 __attribute__((ext_vector_type(4)));
typedef __attribute__((address_space(1))) void* as1_t;
typedef __attribute__((address_space(3))) void* as3_t;

#define LOG2E 1.4426950408889634f
#define MFMA(a,b,c) __builtin_amdgcn_mfma_f32_16x16x32_bf16(a,b,c,0,0,0)

__device__ __forceinline__ u16 f2bf(float f){
  u32 u = __float_as_uint(f);
  return (u16)((u + 0x7FFFu + ((u >> 16) & 1u)) >> 16);
}
__device__ __forceinline__ float bf2f(u16 x){
  return __uint_as_float(((u32)x) << 16);
}
#if __has_builtin(__builtin_amdgcn_cvt_pk_bf16_f32)
__device__ __forceinline__ u16x4 pk4(float a, float b, float c, float d){
  auto lo = __builtin_amdgcn_cvt_pk_bf16_f32(a,b);
  auto hi = __builtin_amdgcn_cvt_pk_bf16_f32(c,d);
  union { u16x4 v; u32 w[2]; } u;
  u.w[0] = __builtin_bit_cast(u32, lo);
  u.w[1] = __builtin_bit_cast(u32, hi);
  return u.v;
}
#else
__device__ __forceinline__ u16x4 pk4(float a, float b, float c, float d){
  u16x4 r = { f2bf(a), f2bf(b), f2bf(c), f2bf(d) };
  return r;
}
#endif
__device__ __forceinline__ void gld16(const u16* gp, u16* lp){
  __builtin_amdgcn_global_load_lds((as1_t)(u16*)gp, (as3_t)lp, 16, 0, 0);
}

#define SBAR  __builtin_amdgcn_s_barrier()
#define SCHB  __builtin_amdgcn_sched_barrier(0)
#define SP1   __builtin_amdgcn_s_setprio(1)
#define SP0   __builtin_amdgcn_s_setprio(0)
#define WAITL0 asm volatile("s_waitcnt lgkmcnt(0)" ::: "memory")
#define WAITV6 asm volatile("s_waitcnt vmcnt(6)" ::: "memory")
#define WV2 asm volatile("s_waitcnt vmcnt(2)" ::: "memory")
#define WV8 asm volatile("s_waitcnt vmcnt(8)" ::: "memory")

// ---------------- prep: cast both inputs + all 5 weight transposes, ONE launch ----------------
__global__ void prep_kernel(const float* __restrict__ vis, u16* __restrict__ vis16,
                            const float* __restrict__ txt, u16* __restrict__ txt16,
                            const float* __restrict__ Wq, const float* __restrict__ Wk,
                            const float* __restrict__ Wv, const float* __restrict__ Wo,
                            u16* __restrict__ T0, u16* __restrict__ T1,
                            u16* __restrict__ T2, u16* __restrict__ T3,
                            u16* __restrict__ T4){
  int bid = blockIdx.x;
  if(bid < 8192){
    const float* src = (bid < 4096) ? vis : txt;
    u16* dst = (bid < 4096) ? vis16 : txt16;
    int idx = ((bid & 4095)*256 + threadIdx.x)*4;
    float4 v = *(const float4*)(src + idx);
    *(u16x4*)(dst + idx) = pk4(v.x, v.y, v.z, v.w);
    return;
  }
  int rr = bid - 8192;
  int wi = rr >> 8, tile = rr & 255;
  const float* W; u16* WT;
  switch(wi){
    case 0: W = Wq; WT = T0; break;
    case 1: W = Wv; WT = T1; break;
    case 2: W = Wk; WT = T2; break;
    case 3: W = Wv; WT = T3; break;
    default: W = Wo; WT = T4; break;
  }
  __shared__ u16 t[64][65];
  int bn = (tile & 15)*64, bk = (tile >> 4)*64;
  int c = threadIdx.x & 63, r0 = threadIdx.x >> 6;
  #pragma unroll
  for(int j=0;j<64;j+=4){
    int r = r0 + j;
    t[r][c] = f2bf(W[(bk + r)*1024 + bn + c]);
  }
  __syncthreads();
  #pragma unroll
  for(int j=0;j<64;j+=4){
    int r = r0 + j;
    WT[(bn + r)*1024 + bk + c] = t[c][r];
  }
}

// ======== proj macros (round-3 structure, 256x256, BK=64, 8 waves 2Mx4N) =====================
#define STG(G, gbase, dsto, kk) { \
    _Pragma("unroll") \
    for(int ii=0;ii<4;ii++){ \
      int slot_ = ii*512 + tid; int r_ = slot_ >> 3, cs_ = slot_ & 7; \
      gld16((G) + (size_t)((gbase) + r_)*1024 + (kk) + ((cs_ ^ (r_ & 7)) << 3), \
            lds + (dsto) + (ii*512 + (w << 6))*8); } }

#define LDA_(bo, mh) { \
    _Pragma("unroll") \
    for(int q_=0;q_<4;q_++){ \
      int ro_ = (bo) + arow + (((mh)*4 + q_) << 10); \
      af[q_][0] = *(const bf16x8*)(lds + ro_ + sx0); \
      af[q_][1] = *(const bf16x8*)(lds + ro_ + sx1); } }

#define LDB_(bo, nh, bfv) { \
    _Pragma("unroll") \
    for(int j_=0;j_<2;j_++){ \
      int ro_ = (bo) + brow + (((nh)*2 + j_) << 10); \
      bfv[j_][0] = *(const bf16x8*)(lds + ro_ + sx0); \
      bfv[j_][1] = *(const bf16x8*)(lds + ro_ + sx1); } }

// normal product: acc[m-frag][n-frag], D = A x B
#define MM_N(mh, bfv, nh) { \
    _Pragma("unroll") \
    for(int q_=0;q_<4;q_++) \
      _Pragma("unroll") \
      for(int j_=0;j_<2;j_++){ \
        int ai_ = ((mh)*4+q_)*4 + (nh)*2+j_; \
        acc[ai_] = MFMA(af[q_][0], bfv[j_][0], acc[ai_]); \
        acc[ai_] = MFMA(af[q_][1], bfv[j_][1], acc[ai_]); } }

// swapped product: acc[n-frag][m-frag] = C^T (A/B fragments share lane->(idx,k) map).
#define MM_T(mh, bfv, nh) { \
    _Pragma("unroll") \
    for(int q_=0;q_<4;q_++) \
      _Pragma("unroll") \
      for(int j_=0;j_<2;j_++){ \
        int ai_ = ((nh)*2+j_)*8 + (mh)*4+q_; \
        acc[ai_] = MFMA(bfv[j_][0], af[q_][0], acc[ai_]); \
        acc[ai_] = MFMA(bfv[j_][1], af[q_][1], acc[ai_]); } }

#define TILE_BODY(bufo, ts, MM) { \
    LDA_(bufo, 0); LDB_(bufo, 0, bfv0); \
    SBAR; WAITL0; SCHB; SP1; MM(0, bfv0, 0); SP0; SBAR; \
    LDB_(bufo, 1, bfv1); \
    SBAR; WAITL0; SCHB; SP1; MM(0, bfv1, 1); SP0; SBAR; \
    LDA_(bufo, 1); \
    SBAR; WAITL0; SCHB; SP1; MM(1, bfv1, 1); SP0; SBAR; \
    STG(A , bm, (bufo)        , ts); \
    STG(Bt, bn, (bufo) + 16384, ts); \
    SCHB; SP1; MM(1, bfv0, 0); SP0; \
    WV8; SBAR; }

// ---------------- merged projection GEMM (round-3 K-loop + coalesced V^T epilogue) -----------
// grid (16 m, 8 n, 2 z): bid%8 = m%8 -> A-panel sharers co-located per XCD.
__global__ __launch_bounds__(512, 2)
void proj_gemm_kernel(const u16* __restrict__ Avis, const u16* __restrict__ Atxt,
                      const u16* __restrict__ Wvis, const u16* __restrict__ Wtxt,
                      u16* __restrict__ Qb, u16* __restrict__ V2t,
                      u16* __restrict__ Kb, u16* __restrict__ Vt)
{
  const u16 *A, *Bt; u16 *Cn, *Ct;
  if(blockIdx.z == 0){ A = Avis; Bt = Wvis; Cn = Qb; Ct = V2t; }
  else               { A = Atxt; Bt = Wtxt; Cn = Kb; Ct = Vt;  }
  __shared__ u16 lds[65536];
  const int tid = threadIdx.x, w = tid >> 6, lane = tid & 63;
  const int quad = lane >> 4, cl = lane & 15;
  const int wr = w >> 2, wc = w & 3;
  const int bm = blockIdx.x*256, bn = blockIdx.y*256;
  const int sx0 = ((quad    ) ^ (cl & 7)) << 3;
  const int sx1 = ((quad + 4) ^ (cl & 7)) << 3;
  const int arow = ((wr << 7) + cl) << 6;
  const int brow = (((wc << 6) + cl) << 6) + 16384;

  f32x4 acc[32];
  #pragma unroll
  for(int a=0;a<32;a++){ f32x4 z = {0.f,0.f,0.f,0.f}; acc[a] = z; }
  bf16x8 af[4][2], bfv0[2][2], bfv1[2][2];

  STG(A , bm, 0,     0);  STG(Bt, bn, 16384, 0);
  STG(A , bm, 32768, 64); STG(Bt, bn, 32768+16384, 64);
  WV8; SBAR;

  if(bn < 1024){
    for(int tt=0; tt<8; tt++){
      const int t0 = 2*tt;
      TILE_BODY(0,     ((t0+2)&15) << 6, MM_N);
      TILE_BODY(32768, ((t0+3)&15) << 6, MM_N);
    }
    #pragma unroll
    for(int mf=0; mf<8; mf++){
      int m0 = bm + wr*128 + mf*16 + quad*4;
      #pragma unroll
      for(int nf=0; nf<4; nf++){
        int n = bn + wc*64 + nf*16 + cl;
        int h = n >> 6, d = n & 63;
        #pragma unroll
        for(int i2=0;i2<4;i2++){
          int m = m0 + i2; int b = m >> 10, s = m & 1023;
          Cn[(((size_t)(b*16 + h)*1024 + s) << 6) + d] = f2bf(acc[mf*4+nf][i2]);
        }
      }
    }
  } else {
    for(int tt=0; tt<8; tt++){
      const int t0 = 2*tt;
      TILE_BODY(0,     ((t0+2)&15) << 6, MM_T);
      TILE_BODY(32768, ((t0+3)&15) << 6, MM_T);
    }
    const int bT = bm >> 10;
    const int sbase = (bm & 1023) + wr*128;
    #pragma unroll
    for(int nf=0; nf<4; nf++){
      #pragma unroll
      for(int i2=0;i2<4;i2++){
        int nn = (bn - 1024) + wc*64 + nf*16 + quad*4 + i2;
        int h = nn >> 6, d = nn & 63;
        u16* rowp = Ct + ((size_t)(bT*16 + h)*64 + d)*1024;
        #pragma unroll
        for(int mf=0; mf<8; mf++)
          rowp[sbase + mf*16 + cl] = f2bf(acc[nf*8+mf][i2]);
      }
    }
  }
}

#undef STG
#undef LDA_
#undef LDB_
#undef MM_N
#undef MM_T
#undef TILE_BODY

// ============ out_gemm body: 256x128 (BK=64) 3-deep pipelined (round-2/3 structure) ==========
__device__ __forceinline__ void gemm_pipe(const u16* __restrict__ A,
                                          const u16* __restrict__ Bt,
                                          int bm, int bn,
                                          u16* __restrict__ lds,
                                          f32x4 (&acc)[4][4],
                                          int tid, int w, int quad, int cl,
                                          int wr, int wc)
{
  const int sx0 = ((quad    ) ^ (cl & 7)) << 3;
  const int sx1 = ((quad + 4) ^ (cl & 7)) << 3;
  const int arow = ((wr << 6) + cl) << 6;
  const int brow = (((wc << 6) + cl) << 6) + 16384;
  bf16x8 af[4][2], bfv[2][2];

#define STAGE128(G, gbase, dsto, kk) { \
    _Pragma("unroll") \
    for(int ii=0;ii<2;ii++){ \
      int slot_ = ii*512 + tid; int r_ = slot_ >> 3, cs_ = slot_ & 7; \
      gld16((G) + (size_t)((gbase) + r_)*1024 + (kk) + ((cs_ ^ (r_ & 7)) << 3), \
            lds + (dsto) + (ii*512 + (w << 6))*8); } }

#define LDA_(bo) { \
    _Pragma("unroll") \
    for(int m_=0;m_<4;m_++){ \
      int ro_ = (bo) + arow + (m_ << 10); \
      af[m_][0] = *(const bf16x8*)(lds + ro_ + sx0); \
      af[m_][1] = *(const bf16x8*)(lds + ro_ + sx1); } }

#define LDB_(bo, nh) { \
    _Pragma("unroll") \
    for(int j_=0;j_<2;j_++){ \
      int ro_ = (bo) + brow + (((nh)*2 + j_) << 10); \
      bfv[j_][0] = *(const bf16x8*)(lds + ro_ + sx0); \
      bfv[j_][1] = *(const bf16x8*)(lds + ro_ + sx1); } }

#define MM_(nh) { \
    _Pragma("unroll") \
    for(int m_=0;m_<4;m_++) \
      _Pragma("unroll") \
      for(int j_=0;j_<2;j_++){ \
        acc[m_][(nh)*2+j_] = MFMA(af[m_][0], bfv[j_][0], acc[m_][(nh)*2+j_]); \
        acc[m_][(nh)*2+j_] = MFMA(af[m_][1], bfv[j_][1], acc[m_][(nh)*2+j_]); } }

  STAGE128(A , bm      , 0,          0);
  STAGE128(A , bm + 128, 8192,       0);
  STAGE128(Bt, bn      , 16384,      0);
  STAGE128(A , bm      , 24576,      64);
  STAGE128(A , bm + 128, 24576+8192, 64);
  STAGE128(Bt, bn      , 24576+16384,64);
  WAITV6; SBAR;

  #pragma unroll 2
  for(int t=0;t<16;t++){
    const int c  = (t % 3) * 24576;
    const int n2 = ((t+2) % 3) * 24576;
    const int ts = ((t+2) & 15) << 6;
    LDA_(c); LDB_(c, 0);
    STAGE128(A, bm      , n2,        ts);
    STAGE128(A, bm + 128, n2 + 8192, ts);
    SBAR; WAITL0; SCHB;
    SP1; MM_(0); SP0;
    SBAR;
    LDB_(c, 1);
    STAGE128(Bt, bn, n2 + 16384, ts);
    SBAR; WAITL0; SCHB;
    SP1; MM_(1); SP0;
    WAITV6;
    SBAR;
  }
#undef STAGE128
#undef LDA_
#undef LDB_
#undef MM_
}

// ---------------- output GEMM: out[8192 x 1024] f32 = A * WoT, 256x128 3-deep pipeline -------
__global__ __launch_bounds__(512, 2)
void out_gemm_kernel(const u16* __restrict__ A, const u16* __restrict__ Bt,
                     float* __restrict__ Cf)
{
  __shared__ u16 lds[73728];
  const int tid = threadIdx.x, w = tid >> 6, lane = tid & 63;
  const int quad = lane >> 4, cl = lane & 15;
  const int wr = w >> 1, wc = w & 1;
  const int bm = blockIdx.x*256, bn = blockIdx.y*128;

  f32x4 acc[4][4];
  #pragma unroll
  for(int a=0;a<4;a++)
    #pragma unroll
    for(int b=0;b<4;b++){ f32x4 z = {0.f,0.f,0.f,0.f}; acc[a][b] = z; }

  gemm_pipe(A, Bt, bm, bn, lds, acc, tid, w, quad, cl, wr, wc);

  #pragma unroll
  for(int mf=0; mf<4; mf++)
    #pragma unroll
    for(int nf=0; nf<4; nf++)
      #pragma unroll
      for(int i=0;i<4;i++){
        int m = bm + wr*64 + mf*16 + quad*4 + i;
        int n = bn + wc*64 + nf*16 + cl;
        Cf[(size_t)m*1024 + n] = acc[mf][nf][i];
      }
}

// ---------------- attention (vis): 8 waves x 16 q-rows; double-buffered K/V, counted vmcnt ---
// Per iter: 2 raw barriers, stage tile t+2 after reads-done barrier, vmcnt(2) drains t+1
// (issued one full compute phase earlier). No vmcnt(0) in-loop (was: __syncthreads full drain).
__global__ __launch_bounds__(512, 4)
void attn_vis_kernel(const u16* __restrict__ Q, const u16* __restrict__ Kc,
                     const u16* __restrict__ Vt, u16* __restrict__ visA,
                     float* __restrict__ rl_g)
{
  __shared__ u16 lds[25600];   // 51.2 KB: P[128][72]=9216 | KV buf0 8192 | KV buf1 8192
  u16* Pl  = lds;
  const int tid = threadIdx.x, w = tid>>6, lane = tid&63;
  const int quad = lane>>4, cl = lane&15;
  const int bh = blockIdx.x, q0 = blockIdx.y*128;   // XCD = bh % 8
  const u16* Qh  = Q  + (size_t)bh*65536;
  const u16* Kh  = Kc + (size_t)bh*65536;
  const u16* Vth = Vt + (size_t)bh*65536;

  #pragma unroll
  for(int i=0;i<2;i++){
    int slot = i*512 + tid;
    int c = slot >> 7, r = slot & 127;
    gld16(Qh + (size_t)(q0 + r)*64 + c*8, Pl + slot*8);
  }
  __syncthreads();
  bf16x8 qf[2];
  #pragma unroll
  for(int kk=0;kk<2;kk++)
    qf[kk] = *(const bf16x8*)(Pl + ((kk*4+quad)*128 + w*16 + cl)*8);
  __syncthreads();   // Pl now becomes the P buffer; vmcnt ledger clean

  // stage one K/V tile (2 gld16/thread) into buffer `buf`
#define KVST(kt, buf) { \
    u16* B_ = lds + 9216 + (buf)*8192; \
    { int c_ = tid >> 6, r_ = tid & 63; \
      gld16(Kh + (size_t)((kt)*64 + r_)*64 + c_*8, B_ + tid*8); } \
    { int d_ = tid >> 3, ch_ = tid & 7; \
      gld16(Vth + (size_t)d_*1024 + (kt)*64 + ((ch_^(d_&7))*8), B_ + 4096 + tid*8); } }

  KVST(0, 0); KVST(1, 1);
  WV2; SBAR;                         // tile0 drained+published; tile1 in flight

  float lrun = 0.f;
  f32x4 oacc[4];
  #pragma unroll
  for(int dt=0;dt<4;dt++){ f32x4 z = {0.f,0.f,0.f,0.f}; oacc[dt] = z; }

  for(int kt=0;kt<16;kt++){
    const int bb = kt & 1;
    u16* Kst = lds + 9216 + bb*8192;
    u16* Vst = Kst + 4096;
    #pragma unroll
    for(int mtk=0;mtk<4;mtk++){
      f32x4 s = {0.f,0.f,0.f,0.f};
      #pragma unroll
      for(int kk=0;kk<2;kk++){
        bf16x8 ka = *(const bf16x8*)(Kst + ((kk*4+quad)*64 + mtk*16 + cl)*8);
        s = MFMA(ka, qf[kk], s);
      }
      float p0 = __builtin_amdgcn_exp2f(s[0]*LOG2E);
      float p1 = __builtin_amdgcn_exp2f(s[1]*LOG2E);
      float p2 = __builtin_amdgcn_exp2f(s[2]*LOG2E);
      float p3 = __builtin_amdgcn_exp2f(s[3]*LOG2E);
      lrun += (p0+p1)+(p2+p3);
      *(u16x4*)(Pl + (w*16 + cl)*72 + mtk*16 + quad*4) = pk4(p0,p1,p2,p3);
    }
    bf16x8 pa[2];
    #pragma unroll
    for(int kk=0;kk<2;kk++)
      pa[kk] = *(const bf16x8*)(Pl + (w*16 + cl)*72 + kk*32 + quad*8);
    #pragma unroll
    for(int dt=0;dt<4;dt++){
      int d = dt*16 + cl;
      #pragma unroll
      for(int kk=0;kk<2;kk++){
        bf16x8 vb = *(const bf16x8*)(Vst + d*64 + (((kk*4+quad)^(d&7))*8));
        oacc[dt] = MFMA(pa[kk], vb, oacc[dt]);
      }
    }
    SBAR;                                   // all waves' reads of buf bb done
    const int nk = (kt < 14) ? kt + 2 : kt; // clamp: benign restage of resident tile
    KVST(nk, bb);
    WV2;                                    // drain tile kt+1 (issued one iter ago)
    SBAR;                                   // publish buf bb^1
  }
#undef KVST
  lrun += __shfl_xor(lrun, 16, 64);
  lrun += __shfl_xor(lrun, 32, 64);
  float rl = 1.f/lrun;
  if(quad == 0) rl_g[bh*1024 + q0 + w*16 + cl] = rl;
  const int b = bh >> 4, h = bh & 15;
  #pragma unroll
  for(int i=0;i<4;i++){
    float rr = __shfl(rl, quad*4 + i, 16);
    int q = q0 + w*16 + quad*4 + i;
    #pragma unroll
    for(int dt=0;dt<4;dt++)
      visA[(size_t)(b*1024 + q)*1024 + h*64 + dt*16 + cl] = f2bf(oacc[dt][i]*rr);
  }
}

// ---------------- attention (txt): double-buffered Q/V2; rl staged to LDS (keeps vmcnt clean)
__global__ __launch_bounds__(512, 4)
void attn_txt_kernel(const u16* __restrict__ Kc, const u16* __restrict__ Q,
                     const u16* __restrict__ V2t, const float* __restrict__ rl_g,
                     u16* __restrict__ txtA)
{
  __shared__ u16 lds[27648];   // 55.3 KB: P 9216 | QV buf0 8192 | QV buf1 8192 | rl 2048 (4KB)
  u16* Pl  = lds;
  u16* rlL = lds + 25600;
  const float* rlF = (const float*)rlL;
  const int tid = threadIdx.x, w = tid>>6, lane = tid&63;
  const int quad = lane>>4, cl = lane&15;
  const int bh = blockIdx.x, k0 = blockIdx.y*128;   // XCD = bh % 8
  const u16* Kh  = Kc  + (size_t)bh*65536;
  const u16* Qh  = Q   + (size_t)bh*65536;
  const u16* Vth = V2t + (size_t)bh*65536;

  #pragma unroll
  for(int i=0;i<2;i++){
    int slot = i*512 + tid;
    int c = slot >> 7, r = slot & 127;
    gld16(Kh + (size_t)(k0 + r)*64 + c*8, Pl + slot*8);
  }
  // stage rl[bh] (1024 f32 = 4KB) once: waves 0-3, 16B/thread
  if(tid < 256)
    gld16((const u16*)(rl_g + (size_t)bh*1024) + tid*8, rlL + tid*8);
  __syncthreads();               // drains K-block + rl; ledger clean+uniform
  bf16x8 kb[2];
  #pragma unroll
  for(int kk=0;kk<2;kk++)
    kb[kk] = *(const bf16x8*)(Pl + ((kk*4+quad)*128 + w*16 + cl)*8);
  __syncthreads();

#define QVST(qt, buf) { \
    u16* B_ = lds + 9216 + (buf)*8192; \
    { int c_ = tid >> 6, r_ = tid & 63; \
      gld16(Qh + (size_t)((qt)*64 + r_)*64 + c_*8, B_ + tid*8); } \
    { int d_ = tid >> 3, ch_ = tid & 7; \
      gld16(Vth + (size_t)d_*1024 + (qt)*64 + ((ch_^(d_&7))*8), B_ + 4096 + tid*8); } }

  QVST(0, 0); QVST(1, 1);
  WV2; SBAR;

  f32x4 oacc[4];
  #pragma unroll
  for(int dt=0;dt<4;dt++){ f32x4 z = {0.f,0.f,0.f,0.f}; oacc[dt] = z; }

  for(int qt=0;qt<16;qt++){
    const int bb = qt & 1;
    u16* Qst = lds + 9216 + bb*8192;
    u16* Vst = Qst + 4096;
    f32x4 rv[4];
    #pragma unroll
    for(int mtq=0;mtq<4;mtq++)
      rv[mtq] = *(const f32x4*)(rlF + qt*64 + mtq*16 + quad*4);   // LDS read (lgkm)
    #pragma unroll
    for(int mtq=0;mtq<4;mtq++){
      f32x4 s = {0.f,0.f,0.f,0.f};
      #pragma unroll
      for(int kk=0;kk<2;kk++){
        bf16x8 qa = *(const bf16x8*)(Qst + ((kk*4+quad)*64 + mtq*16 + cl)*8);
        s = MFMA(qa, kb[kk], s);
      }
      float p0 = __builtin_amdgcn_exp2f(s[0]*LOG2E)*rv[mtq][0];
      float p1 = __builtin_amdgcn_exp2f(s[1]*LOG2E)*rv[mtq][1];
      float p2 = __builtin_amdgcn_exp2f(s[2]*LOG2E)*rv[mtq][2];
      float p3 = __builtin_amdgcn_exp2f(s[3]*LOG2E)*rv[mtq][3];
      *(u16x4*)(Pl + (w*16 + cl)*72 + mtq*16 + quad*4) = pk4(p0,p1,p2,p3);
    }
    bf16x8 pa[2];
    #pragma unroll
    for(int kk=0;kk<2;kk++)
      pa[kk] = *(const bf16x8*)(Pl + (w*16 + cl)*72 + kk*32 + quad*8);
    #pragma unroll
    for(int dt=0;dt<4;dt++){
      int d = dt*16 + cl;
      #pragma unroll
      for(int kk=0;kk<2;kk++){
        bf16x8 vb = *(const bf16x8*)(Vst + d*64 + (((kk*4+quad)^(d&7))*8));
        oacc[dt] = MFMA(pa[kk], vb, oacc[dt]);
      }
    }
    SBAR;
    const int nq = (qt < 14) ? qt + 2 : qt;
    QVST(nq, bb);
    WV2;
    SBAR;
  }
#undef QVST
  const int b = bh >> 4, h = bh & 15;
  #pragma unroll
  for(int i=0;i<4;i++){
    int k = k0 + w*16 + quad*4 + i;
    #pragma unroll
    for(int dt=0;dt<4;dt++)
      txtA[(size_t)(b*1024 + k)*1024 + h*64 + dt*16 + cl] = f2bf(oacc[dt][i]);
  }
}

extern "C" void kernel_launch(void* const* d_in, const int* in_sizes, int n_in,
                              void* d_out, int out_size, void* d_ws, size_t ws_size,
                              hipStream_t stream)
{
  const float* vis = (const float*)d_in[0];
  const float* txt = (const float*)d_in[1];
  const float* Wq  = (const float*)d_in[2];
  const float* Wk  = (const float*)d_in[3];
  const float* Wv  = (const float*)d_in[4];
  const float* Wo  = (const float*)d_in[5];
  float* out = (float*)d_out;

  char* ws = (char*)d_ws;
  const size_t MB = 1u << 20;
  u16* vis16 = (u16*)(ws + 0);           // later: visA
  u16* txt16 = (u16*)(ws + 8*MB);        // later: txtA (contiguous with visA for out GEMM)
  u16* Wvis  = (u16*)(ws + 16*MB);       // [WqT | WvT]
  u16* Wtxt  = (u16*)(ws + 20*MB);       // [WkT | WvT]
  u16* Qb    = (u16*)(ws + 24*MB);
  u16* Kb    = (u16*)(ws + 32*MB);
  u16* Vt    = (u16*)(ws + 40*MB);       // V^T  [b][h][d][s]  (from txt proj)
  u16* V2t   = (u16*)(ws + 48*MB);       // V2^T [b][h][d][s]  (from vis proj)
  float* rl_g = (float*)(ws + 56*MB);
  u16* WoT   = (u16*)(ws + 57*MB);
  u16* visA = vis16;  u16* txtA = txt16;

  // 1: cast both inputs + 5 weight transposes
  prep_kernel<<<9472, 256, 0, stream>>>(vis, vis16, txt, txt16,
                                        Wq, Wk, Wv, Wo,
                                        Wvis, Wvis + 1048576, Wtxt, Wtxt + 1048576, WoT);
  // 2: merged projections (round-3 K-loop + coalesced V^T epilogue), 256 blocks (1/CU)
  proj_gemm_kernel<<<dim3(16,8,2), 512, 0, stream>>>(vis16, txt16, Wvis, Wtxt,
                                                     Qb, V2t, Kb, Vt);
  // 3: attention vis (produces rl); double-buffered K/V staging
  attn_vis_kernel<<<dim3(64,8), 512, 0, stream>>>(Qb, Kb, Vt, visA, rl_g);
  // 4: attention txt (rl via LDS); double-buffered Q/V2 staging
  attn_txt_kernel<<<dim3(64,8), 512, 0, stream>>>(Kb, Qb, V2t, rl_g, txtA);
  // 5: merged output projection: M=8192 over visA||txtA (contiguous), f32 out
  out_gemm_kernel<<<dim3(32,8), 512, 0, stream>>>(visA, WoT, out);
}

// Round 10
// 209.515 us; speedup vs baseline: 1.7861x; 1.0256x over previous
//
#include <hip/hip_runtime.h>

typedef unsigned short u16;
typedef unsigned int u32;
typedef __bf16 bf16x8 __attribute__((ext_vector_type(8)));
typedef float f32x4 __attribute__((ext_vector_type(4)));
typedef u16 u16x4 __attribute__((ext_vector_type(4)));
typedef __attribute__((address_space(1))) void* as1_t;
typedef __attribute__((address_space(3))) void* as3_t;

#define LOG2E 1.4426950408889634f
#define MFMA(a,b,c) __builtin_amdgcn_mfma_f32_16x16x32_bf16(a,b,c,0,0,0)

__device__ __forceinline__ u16 f2bf(float f){
  u32 u = __float_as_uint(f);
  return (u16)((u + 0x7FFFu + ((u >> 16) & 1u)) >> 16);
}
__device__ __forceinline__ float bf2f(u16 x){
  return __uint_as_float(((u32)x) << 16);
}
#if __has_builtin(__builtin_amdgcn_cvt_pk_bf16_f32)
__device__ __forceinline__ u16x4 pk4(float a, float b, float c, float d){
  auto lo = __builtin_amdgcn_cvt_pk_bf16_f32(a,b);
  auto hi = __builtin_amdgcn_cvt_pk_bf16_f32(c,d);
  union { u16x4 v; u32 w[2]; } u;
  u.w[0] = __builtin_bit_cast(u32, lo);
  u.w[1] = __builtin_bit_cast(u32, hi);
  return u.v;
}
#else
__device__ __forceinline__ u16x4 pk4(float a, float b, float c, float d){
  u16x4 r = { f2bf(a), f2bf(b), f2bf(c), f2bf(d) };
  return r;
}
#endif
__device__ __forceinline__ void gld16(const u16* gp, u16* lp){
  __builtin_amdgcn_global_load_lds((as1_t)(u16*)gp, (as3_t)lp, 16, 0, 0);
}

#define SBAR  __builtin_amdgcn_s_barrier()
#define SCHB  __builtin_amdgcn_sched_barrier(0)
#define SP1   __builtin_amdgcn_s_setprio(1)
#define SP0   __builtin_amdgcn_s_setprio(0)
#define WAITL0 asm volatile("s_waitcnt lgkmcnt(0)" ::: "memory")
#define WV2 asm volatile("s_waitcnt vmcnt(2)" ::: "memory")
#define WV8 asm volatile("s_waitcnt vmcnt(8)" ::: "memory")

// ---------------- prep: cast both inputs + all 5 weight transposes, ONE launch ----------------
__global__ void prep_kernel(const float* __restrict__ vis, u16* __restrict__ vis16,
                            const float* __restrict__ txt, u16* __restrict__ txt16,
                            const float* __restrict__ Wq, const float* __restrict__ Wk,
                            const float* __restrict__ Wv, const float* __restrict__ Wo,
                            u16* __restrict__ T0, u16* __restrict__ T1,
                            u16* __restrict__ T2, u16* __restrict__ T3,
                            u16* __restrict__ T4){
  int bid = blockIdx.x;
  if(bid < 8192){
    const float* src = (bid < 4096) ? vis : txt;
    u16* dst = (bid < 4096) ? vis16 : txt16;
    int idx = ((bid & 4095)*256 + threadIdx.x)*4;
    float4 v = *(const float4*)(src + idx);
    *(u16x4*)(dst + idx) = pk4(v.x, v.y, v.z, v.w);
    return;
  }
  int rr = bid - 8192;
  int wi = rr >> 8, tile = rr & 255;
  const float* W; u16* WT;
  switch(wi){
    case 0: W = Wq; WT = T0; break;
    case 1: W = Wv; WT = T1; break;
    case 2: W = Wk; WT = T2; break;
    case 3: W = Wv; WT = T3; break;
    default: W = Wo; WT = T4; break;
  }
  __shared__ u16 t[64][65];
  int bn = (tile & 15)*64, bk = (tile >> 4)*64;
  int c = threadIdx.x & 63, r0 = threadIdx.x >> 6;
  #pragma unroll
  for(int j=0;j<64;j+=4){
    int r = r0 + j;
    t[r][c] = f2bf(W[(bk + r)*1024 + bn + c]);
  }
  __syncthreads();
  #pragma unroll
  for(int j=0;j<64;j+=4){
    int r = r0 + j;
    WT[(bn + r)*1024 + bk + c] = t[c][r];
  }
}

// ======== proj macros (round-3 structure, 256x256, BK=64, 8 waves 2Mx4N) =====================
#define STG(G, gbase, dsto, kk) { \
    _Pragma("unroll") \
    for(int ii=0;ii<4;ii++){ \
      int slot_ = ii*512 + tid; int r_ = slot_ >> 3, cs_ = slot_ & 7; \
      gld16((G) + (size_t)((gbase) + r_)*1024 + (kk) + ((cs_ ^ (r_ & 7)) << 3), \
            lds + (dsto) + (ii*512 + (w << 6))*8); } }

#define LDA_(bo, mh) { \
    _Pragma("unroll") \
    for(int q_=0;q_<4;q_++){ \
      int ro_ = (bo) + arow + (((mh)*4 + q_) << 10); \
      af[q_][0] = *(const bf16x8*)(lds + ro_ + sx0); \
      af[q_][1] = *(const bf16x8*)(lds + ro_ + sx1); } }

#define LDB_(bo, nh, bfv) { \
    _Pragma("unroll") \
    for(int j_=0;j_<2;j_++){ \
      int ro_ = (bo) + brow + (((nh)*2 + j_) << 10); \
      bfv[j_][0] = *(const bf16x8*)(lds + ro_ + sx0); \
      bfv[j_][1] = *(const bf16x8*)(lds + ro_ + sx1); } }

// normal product: acc[m-frag][n-frag], D = A x B
#define MM_N(mh, bfv, nh) { \
    _Pragma("unroll") \
    for(int q_=0;q_<4;q_++) \
      _Pragma("unroll") \
      for(int j_=0;j_<2;j_++){ \
        int ai_ = ((mh)*4+q_)*4 + (nh)*2+j_; \
        acc[ai_] = MFMA(af[q_][0], bfv[j_][0], acc[ai_]); \
        acc[ai_] = MFMA(af[q_][1], bfv[j_][1], acc[ai_]); } }

// swapped product: acc[n-frag][m-frag] = C^T (A/B fragments share lane->(idx,k) map).
#define MM_T(mh, bfv, nh) { \
    _Pragma("unroll") \
    for(int q_=0;q_<4;q_++) \
      _Pragma("unroll") \
      for(int j_=0;j_<2;j_++){ \
        int ai_ = ((nh)*2+j_)*8 + (mh)*4+q_; \
        acc[ai_] = MFMA(bfv[j_][0], af[q_][0], acc[ai_]); \
        acc[ai_] = MFMA(bfv[j_][1], af[q_][1], acc[ai_]); } }

#define TILE_BODY(bufo, ts, MM) { \
    LDA_(bufo, 0); LDB_(bufo, 0, bfv0); \
    SBAR; WAITL0; SCHB; SP1; MM(0, bfv0, 0); SP0; SBAR; \
    LDB_(bufo, 1, bfv1); \
    SBAR; WAITL0; SCHB; SP1; MM(0, bfv1, 1); SP0; SBAR; \
    LDA_(bufo, 1); \
    SBAR; WAITL0; SCHB; SP1; MM(1, bfv1, 1); SP0; SBAR; \
    STG(A , bm, (bufo)        , ts); \
    STG(Bt, bn, (bufo) + 16384, ts); \
    SCHB; SP1; MM(1, bfv0, 0); SP0; \
    WV8; SBAR; }

// ---------------- merged projection GEMM (round-3 K-loop + coalesced V^T epilogue) -----------
// grid (16 m, 8 n, 2 z): bid%8 = m%8 -> A-panel sharers co-located per XCD.
__global__ __launch_bounds__(512, 2)
void proj_gemm_kernel(const u16* __restrict__ Avis, const u16* __restrict__ Atxt,
                      const u16* __restrict__ Wvis, const u16* __restrict__ Wtxt,
                      u16* __restrict__ Qb, u16* __restrict__ V2t,
                      u16* __restrict__ Kb, u16* __restrict__ Vt)
{
  const u16 *A, *Bt; u16 *Cn, *Ct;
  if(blockIdx.z == 0){ A = Avis; Bt = Wvis; Cn = Qb; Ct = V2t; }
  else               { A = Atxt; Bt = Wtxt; Cn = Kb; Ct = Vt;  }
  __shared__ u16 lds[65536];
  const int tid = threadIdx.x, w = tid >> 6, lane = tid & 63;
  const int quad = lane >> 4, cl = lane & 15;
  const int wr = w >> 2, wc = w & 3;
  const int bm = blockIdx.x*256, bn = blockIdx.y*256;
  const int sx0 = ((quad    ) ^ (cl & 7)) << 3;
  const int sx1 = ((quad + 4) ^ (cl & 7)) << 3;
  const int arow = ((wr << 7) + cl) << 6;
  const int brow = (((wc << 6) + cl) << 6) + 16384;

  f32x4 acc[32];
  #pragma unroll
  for(int a=0;a<32;a++){ f32x4 z = {0.f,0.f,0.f,0.f}; acc[a] = z; }
  bf16x8 af[4][2], bfv0[2][2], bfv1[2][2];

  STG(A , bm, 0,     0);  STG(Bt, bn, 16384, 0);
  STG(A , bm, 32768, 64); STG(Bt, bn, 32768+16384, 64);
  WV8; SBAR;

  if(bn < 1024){
    for(int tt=0; tt<8; tt++){
      const int t0 = 2*tt;
      TILE_BODY(0,     ((t0+2)&15) << 6, MM_N);
      TILE_BODY(32768, ((t0+3)&15) << 6, MM_N);
    }
    #pragma unroll
    for(int mf=0; mf<8; mf++){
      int m0 = bm + wr*128 + mf*16 + quad*4;
      #pragma unroll
      for(int nf=0; nf<4; nf++){
        int n = bn + wc*64 + nf*16 + cl;
        int h = n >> 6, d = n & 63;
        #pragma unroll
        for(int i2=0;i2<4;i2++){
          int m = m0 + i2; int b = m >> 10, s = m & 1023;
          Cn[(((size_t)(b*16 + h)*1024 + s) << 6) + d] = f2bf(acc[mf*4+nf][i2]);
        }
      }
    }
  } else {
    for(int tt=0; tt<8; tt++){
      const int t0 = 2*tt;
      TILE_BODY(0,     ((t0+2)&15) << 6, MM_T);
      TILE_BODY(32768, ((t0+3)&15) << 6, MM_T);
    }
    const int bT = bm >> 10;
    const int sbase = (bm & 1023) + wr*128;
    #pragma unroll
    for(int nf=0; nf<4; nf++){
      #pragma unroll
      for(int i2=0;i2<4;i2++){
        int nn = (bn - 1024) + wc*64 + nf*16 + quad*4 + i2;
        int h = nn >> 6, d = nn & 63;
        u16* rowp = Ct + ((size_t)(bT*16 + h)*64 + d)*1024;
        #pragma unroll
        for(int mf=0; mf<8; mf++)
          rowp[sbase + mf*16 + cl] = f2bf(acc[nf*8+mf][i2]);
      }
    }
  }
}

#undef STG
#undef LDA_
#undef LDB_
#undef MM_N
#undef MM_T
#undef TILE_BODY

// ---------------- output GEMM: m97-style 128x128, 4 waves, 2-buf, 1 sync/tile, 2 blocks/CU ---
// out[8192x1024] f32 = A[8192x1024] x WoT. grid (64 m, 8 n) = 512 blocks (2/CU): the per-tile
// vmcnt0 drain inside __syncthreads hides under the co-resident block's compute (m97: 912 TF).
// bid%8 = m%8 -> the 8 A-panel sharers co-located per XCD.
#define STGO(G, gbase, dsto, kk) { \
    _Pragma("unroll") \
    for(int ii=0;ii<4;ii++){ \
      int slot_ = ii*256 + tid; int r_ = slot_ >> 3, cs_ = slot_ & 7; \
      gld16((G) + (size_t)((gbase) + r_)*1024 + (kk) + ((cs_ ^ (r_ & 7)) << 3), \
            lds + (dsto) + (ii*256 + (w << 6))*8); } }

__global__ __launch_bounds__(256, 2)
void out_gemm_kernel(const u16* __restrict__ A, const u16* __restrict__ Bt,
                     float* __restrict__ Cf)
{
  __shared__ u16 lds[32768];           // 64 KiB: buf c at c*16384: A[128][64] | B[128][64]
  const int tid = threadIdx.x, w = tid >> 6, lane = tid & 63;
  const int quad = lane >> 4, cl = lane & 15;
  const int wr = w >> 1, wc = w & 1;   // 2x2 waves, 64x64 per wave
  const int bm = blockIdx.x*128, bn = blockIdx.y*128;
  const int sx0 = ((quad    ) ^ (cl & 7)) << 3;
  const int sx1 = ((quad + 4) ^ (cl & 7)) << 3;
  const int arow = ((wr << 6) + cl) << 6;
  const int brow = (((wc << 6) + cl) << 6) + 8192;

  f32x4 acc[4][4];
  #pragma unroll
  for(int a=0;a<4;a++)
    #pragma unroll
    for(int b=0;b<4;b++){ f32x4 z = {0.f,0.f,0.f,0.f}; acc[a][b] = z; }
  bf16x8 af[4][2], bfv[4][2];

  STGO(A , bm, 0,    0);
  STGO(Bt, bn, 8192, 0);
  __syncthreads();

  #pragma unroll 2
  for(int t=0; t<16; ++t){
    const int c  = (t & 1) << 14;
    const int nb = c ^ 16384;
    if(t < 15){                        // stage tile t+1 into the other buffer (reads done)
      STGO(A , bm, nb,        (t+1) << 6);
      STGO(Bt, bn, nb + 8192, (t+1) << 6);
    }
    #pragma unroll
    for(int m=0;m<4;m++){
      int ro = c + arow + (m << 10);
      af[m][0] = *(const bf16x8*)(lds + ro + sx0);
      af[m][1] = *(const bf16x8*)(lds + ro + sx1);
    }
    #pragma unroll
    for(int n=0;n<4;n++){
      int ro = c + brow + (n << 10);
      bfv[n][0] = *(const bf16x8*)(lds + ro + sx0);
      bfv[n][1] = *(const bf16x8*)(lds + ro + sx1);
    }
    SP1;
    #pragma unroll
    for(int m=0;m<4;m++)
      #pragma unroll
      for(int n=0;n<4;n++){
        acc[m][n] = MFMA(af[m][0], bfv[n][0], acc[m][n]);
        acc[m][n] = MFMA(af[m][1], bfv[n][1], acc[m][n]);
      }
    SP0;
    __syncthreads();                   // drains staged tile t+1 + all reads of buf c
  }

  #pragma unroll
  for(int mf=0; mf<4; mf++)
    #pragma unroll
    for(int nf=0; nf<4; nf++)
      #pragma unroll
      for(int i=0;i<4;i++){
        int m = bm + wr*64 + mf*16 + quad*4 + i;
        int n = bn + wc*64 + nf*16 + cl;
        Cf[(size_t)m*1024 + n] = acc[mf][nf][i];
      }
}
#undef STGO

// ---------------- attention (vis): 8 waves x 16 q-rows; double-buffered K/V, counted vmcnt ---
__global__ __launch_bounds__(512, 4)
void attn_vis_kernel(const u16* __restrict__ Q, const u16* __restrict__ Kc,
                     const u16* __restrict__ Vt, u16* __restrict__ visA,
                     float* __restrict__ rl_g)
{
  __shared__ u16 lds[25600];   // 51.2 KB: P[128][72]=9216 | KV buf0 8192 | KV buf1 8192
  u16* Pl  = lds;
  const int tid = threadIdx.x, w = tid>>6, lane = tid&63;
  const int quad = lane>>4, cl = lane&15;
  const int bh = blockIdx.x, q0 = blockIdx.y*128;   // XCD = bh % 8
  const u16* Qh  = Q  + (size_t)bh*65536;
  const u16* Kh  = Kc + (size_t)bh*65536;
  const u16* Vth = Vt + (size_t)bh*65536;

  #pragma unroll
  for(int i=0;i<2;i++){
    int slot = i*512 + tid;
    int c = slot >> 7, r = slot & 127;
    gld16(Qh + (size_t)(q0 + r)*64 + c*8, Pl + slot*8);
  }
  __syncthreads();
  bf16x8 qf[2];
  #pragma unroll
  for(int kk=0;kk<2;kk++)
    qf[kk] = *(const bf16x8*)(Pl + ((kk*4+quad)*128 + w*16 + cl)*8);
  __syncthreads();   // Pl now becomes the P buffer; vmcnt ledger clean

#define KVST(kt, buf) { \
    u16* B_ = lds + 9216 + (buf)*8192; \
    { int c_ = tid >> 6, r_ = tid & 63; \
      gld16(Kh + (size_t)((kt)*64 + r_)*64 + c_*8, B_ + tid*8); } \
    { int d_ = tid >> 3, ch_ = tid & 7; \
      gld16(Vth + (size_t)d_*1024 + (kt)*64 + ((ch_^(d_&7))*8), B_ + 4096 + tid*8); } }

  KVST(0, 0); KVST(1, 1);
  WV2; SBAR;                         // tile0 drained+published; tile1 in flight

  float lrun = 0.f;
  f32x4 oacc[4];
  #pragma unroll
  for(int dt=0;dt<4;dt++){ f32x4 z = {0.f,0.f,0.f,0.f}; oacc[dt] = z; }

  for(int kt=0;kt<16;kt++){
    const int bb = kt & 1;
    u16* Kst = lds + 9216 + bb*8192;
    u16* Vst = Kst + 4096;
    #pragma unroll
    for(int mtk=0;mtk<4;mtk++){
      f32x4 s = {0.f,0.f,0.f,0.f};
      #pragma unroll
      for(int kk=0;kk<2;kk++){
        bf16x8 ka = *(const bf16x8*)(Kst + ((kk*4+quad)*64 + mtk*16 + cl)*8);
        s = MFMA(ka, qf[kk], s);
      }
      float p0 = __builtin_amdgcn_exp2f(s[0]*LOG2E);
      float p1 = __builtin_amdgcn_exp2f(s[1]*LOG2E);
      float p2 = __builtin_amdgcn_exp2f(s[2]*LOG2E);
      float p3 = __builtin_amdgcn_exp2f(s[3]*LOG2E);
      lrun += (p0+p1)+(p2+p3);
      *(u16x4*)(Pl + (w*16 + cl)*72 + mtk*16 + quad*4) = pk4(p0,p1,p2,p3);
    }
    bf16x8 pa[2];
    #pragma unroll
    for(int kk=0;kk<2;kk++)
      pa[kk] = *(const bf16x8*)(Pl + (w*16 + cl)*72 + kk*32 + quad*8);
    #pragma unroll
    for(int dt=0;dt<4;dt++){
      int d = dt*16 + cl;
      #pragma unroll
      for(int kk=0;kk<2;kk++){
        bf16x8 vb = *(const bf16x8*)(Vst + d*64 + (((kk*4+quad)^(d&7))*8));
        oacc[dt] = MFMA(pa[kk], vb, oacc[dt]);
      }
    }
    SBAR;                                   // all waves' reads of buf bb done
    const int nk = (kt < 14) ? kt + 2 : kt; // clamp: benign restage of resident tile
    KVST(nk, bb);
    WV2;                                    // drain tile kt+1 (issued one iter ago)
    SBAR;                                   // publish buf bb^1
  }
#undef KVST
  lrun += __shfl_xor(lrun, 16, 64);
  lrun += __shfl_xor(lrun, 32, 64);
  float rl = 1.f/lrun;
  if(quad == 0) rl_g[bh*1024 + q0 + w*16 + cl] = rl;
  const int b = bh >> 4, h = bh & 15;
  #pragma unroll
  for(int i=0;i<4;i++){
    float rr = __shfl(rl, quad*4 + i, 16);
    int q = q0 + w*16 + quad*4 + i;
    #pragma unroll
    for(int dt=0;dt<4;dt++)
      visA[(size_t)(b*1024 + q)*1024 + h*64 + dt*16 + cl] = f2bf(oacc[dt][i]*rr);
  }
}

// ---------------- attention (txt): double-buffered Q/V2; rl staged to LDS (keeps vmcnt clean)
__global__ __launch_bounds__(512, 4)
void attn_txt_kernel(const u16* __restrict__ Kc, const u16* __restrict__ Q,
                     const u16* __restrict__ V2t, const float* __restrict__ rl_g,
                     u16* __restrict__ txtA)
{
  __shared__ u16 lds[27648];   // 55.3 KB: P 9216 | QV buf0 8192 | QV buf1 8192 | rl 2048
  u16* Pl  = lds;
  u16* rlL = lds + 25600;
  const float* rlF = (const float*)rlL;
  const int tid = threadIdx.x, w = tid>>6, lane = tid&63;
  const int quad = lane>>4, cl = lane&15;
  const int bh = blockIdx.x, k0 = blockIdx.y*128;   // XCD = bh % 8
  const u16* Kh  = Kc  + (size_t)bh*65536;
  const u16* Qh  = Q   + (size_t)bh*65536;
  const u16* Vth = V2t + (size_t)bh*65536;

  #pragma unroll
  for(int i=0;i<2;i++){
    int slot = i*512 + tid;
    int c = slot >> 7, r = slot & 127;
    gld16(Kh + (size_t)(k0 + r)*64 + c*8, Pl + slot*8);
  }
  if(tid < 256)
    gld16((const u16*)(rl_g + (size_t)bh*1024) + tid*8, rlL + tid*8);
  __syncthreads();               // drains K-block + rl; ledger clean+uniform
  bf16x8 kb[2];
  #pragma unroll
  for(int kk=0;kk<2;kk++)
    kb[kk] = *(const bf16x8*)(Pl + ((kk*4+quad)*128 + w*16 + cl)*8);
  __syncthreads();

#define QVST(qt, buf) { \
    u16* B_ = lds + 9216 + (buf)*8192; \
    { int c_ = tid >> 6, r_ = tid & 63; \
      gld16(Qh + (size_t)((qt)*64 + r_)*64 + c_*8, B_ + tid*8); } \
    { int d_ = tid >> 3, ch_ = tid & 7; \
      gld16(Vth + (size_t)d_*1024 + (qt)*64 + ((ch_^(d_&7))*8), B_ + 4096 + tid*8); } }

  QVST(0, 0); QVST(1, 1);
  WV2; SBAR;

  f32x4 oacc[4];
  #pragma unroll
  for(int dt=0;dt<4;dt++){ f32x4 z = {0.f,0.f,0.f,0.f}; oacc[dt] = z; }

  for(int qt=0;qt<16;qt++){
    const int bb = qt & 1;
    u16* Qst = lds + 9216 + bb*8192;
    u16* Vst = Qst + 4096;
    f32x4 rv[4];
    #pragma unroll
    for(int mtq=0;mtq<4;mtq++)
      rv[mtq] = *(const f32x4*)(rlF + qt*64 + mtq*16 + quad*4);   // LDS read (lgkm)
    #pragma unroll
    for(int mtq=0;mtq<4;mtq++){
      f32x4 s = {0.f,0.f,0.f,0.f};
      #pragma unroll
      for(int kk=0;kk<2;kk++){
        bf16x8 qa = *(const bf16x8*)(Qst + ((kk*4+quad)*64 + mtq*16 + cl)*8);
        s = MFMA(qa, kb[kk], s);
      }
      float p0 = __builtin_amdgcn_exp2f(s[0]*LOG2E)*rv[mtq][0];
      float p1 = __builtin_amdgcn_exp2f(s[1]*LOG2E)*rv[mtq][1];
      float p2 = __builtin_amdgcn_exp2f(s[2]*LOG2E)*rv[mtq][2];
      float p3 = __builtin_amdgcn_exp2f(s[3]*LOG2E)*rv[mtq][3];
      *(u16x4*)(Pl + (w*16 + cl)*72 + mtq*16 + quad*4) = pk4(p0,p1,p2,p3);
    }
    bf16x8 pa[2];
    #pragma unroll
    for(int kk=0;kk<2;kk++)
      pa[kk] = *(const bf16x8*)(Pl + (w*16 + cl)*72 + kk*32 + quad*8);
    #pragma unroll
    for(int dt=0;dt<4;dt++){
      int d = dt*16 + cl;
      #pragma unroll
      for(int kk=0;kk<2;kk++){
        bf16x8 vb = *(const bf16x8*)(Vst + d*64 + (((kk*4+quad)^(d&7))*8));
        oacc[dt] = MFMA(pa[kk], vb, oacc[dt]);
      }
    }
    SBAR;
    const int nq = (qt < 14) ? qt + 2 : qt;
    QVST(nq, bb);
    WV2;
    SBAR;
  }
#undef QVST
  const int b = bh >> 4, h = bh & 15;
  #pragma unroll
  for(int i=0;i<4;i++){
    int k = k0 + w*16 + quad*4 + i;
    #pragma unroll
    for(int dt=0;dt<4;dt++)
      txtA[(size_t)(b*1024 + k)*1024 + h*64 + dt*16 + cl] = f2bf(oacc[dt][i]);
  }
}

extern "C" void kernel_launch(void* const* d_in, const int* in_sizes, int n_in,
                              void* d_out, int out_size, void* d_ws, size_t ws_size,
                              hipStream_t stream)
{
  const float* vis = (const float*)d_in[0];
  const float* txt = (const float*)d_in[1];
  const float* Wq  = (const float*)d_in[2];
  const float* Wk  = (const float*)d_in[3];
  const float* Wv  = (const float*)d_in[4];
  const float* Wo  = (const float*)d_in[5];
  float* out = (float*)d_out;

  char* ws = (char*)d_ws;
  const size_t MB = 1u << 20;
  u16* vis16 = (u16*)(ws + 0);           // later: visA
  u16* txt16 = (u16*)(ws + 8*MB);        // later: txtA (contiguous with visA for out GEMM)
  u16* Wvis  = (u16*)(ws + 16*MB);       // [WqT | WvT]
  u16* Wtxt  = (u16*)(ws + 20*MB);       // [WkT | WvT]
  u16* Qb    = (u16*)(ws + 24*MB);
  u16* Kb    = (u16*)(ws + 32*MB);
  u16* Vt    = (u16*)(ws + 40*MB);       // V^T  [b][h][d][s]  (from txt proj)
  u16* V2t   = (u16*)(ws + 48*MB);       // V2^T [b][h][d][s]  (from vis proj)
  float* rl_g = (float*)(ws + 56*MB);
  u16* WoT   = (u16*)(ws + 57*MB);
  u16* visA = vis16;  u16* txtA = txt16;

  // 1: cast both inputs + 5 weight transposes
  prep_kernel<<<9472, 256, 0, stream>>>(vis, vis16, txt, txt16,
                                        Wq, Wk, Wv, Wo,
                                        Wvis, Wvis + 1048576, Wtxt, Wtxt + 1048576, WoT);
  // 2: merged projections (round-3 K-loop + coalesced V^T epilogue), 256 blocks (1/CU)
  proj_gemm_kernel<<<dim3(16,8,2), 512, 0, stream>>>(vis16, txt16, Wvis, Wtxt,
                                                     Qb, V2t, Kb, Vt);
  // 3: attention vis (produces rl); double-buffered K/V staging
  attn_vis_kernel<<<dim3(64,8), 512, 0, stream>>>(Qb, Kb, Vt, visA, rl_g);
  // 4: attention txt (rl via LDS); double-buffered Q/V2 staging
  attn_txt_kernel<<<dim3(64,8), 512, 0, stream>>>(Kb, Qb, V2t, rl_g, txtA);
  // 5: merged output projection, m97-style 128x128, 512 blocks (2/CU)
  out_gemm_kernel<<<dim3(64,8), 256, 0, stream>>>(visA, WoT, out);
}